// Round 5
// baseline (180.540 us; speedup 1.0000x reference)
//
#include <hip/hip_runtime.h>
#include <stdint.h>

typedef __attribute__((ext_vector_type(8))) short short8;
typedef __attribute__((ext_vector_type(8))) unsigned short ushort8;
typedef __attribute__((ext_vector_type(4))) float f32x4;
typedef unsigned short u16;
typedef unsigned int u32;

// RNE f32 -> bf16 bits
__device__ __forceinline__ u16 f2bf(float f){
  u32 u = __builtin_bit_cast(u32, f);
  u32 r = (u + 0x7fffu + ((u >> 16) & 1u)) >> 16;
  return (u16)r;
}

__device__ __forceinline__ void gload16(const void* g, void* l){
  __builtin_amdgcn_global_load_lds((const __attribute__((address_space(1))) void*)g,
                                   (__attribute__((address_space(3))) void*)l, 16, 0, 0);
}

// ---------------- cast q,k,v -> bf16 (16B stores) ----------------
__global__ void cast3_kernel(const float* __restrict__ q, const float* __restrict__ k,
                             const float* __restrict__ v, u16* __restrict__ xq,
                             u16* __restrict__ xk, u16* __restrict__ xv){
  const int NV8 = 4194304 / 8;
  int stride = gridDim.x * blockDim.x;
  for (int i = blockIdx.x * blockDim.x + threadIdx.x; i < 3 * NV8; i += stride){
    int t = i / NV8, r = i - t * NV8;
    const float4* src = (const float4*)(t == 0 ? q : (t == 1 ? k : v));
    u16* dst = (t == 0 ? xq : (t == 1 ? xk : xv));
    float4 f0 = src[r * 2], f1 = src[r * 2 + 1];
    ushort8 o;
    o[0] = f2bf(f0.x); o[1] = f2bf(f0.y); o[2] = f2bf(f0.z); o[3] = f2bf(f0.w);
    o[4] = f2bf(f1.x); o[5] = f2bf(f1.y); o[6] = f2bf(f1.z); o[7] = f2bf(f1.w);
    *(ushort8*)(dst + r * 8) = o;
  }
}

// ---------------- transpose + cast weights ----------------
__global__ void transw_kernel(const float* __restrict__ Wq, const float* __restrict__ Wk,
                              const float* __restrict__ Wv, const float* __restrict__ Wo,
                              u16* __restrict__ WqT, u16* __restrict__ WkT,
                              u16* __restrict__ WvT, u16* __restrict__ WoT){
  __shared__ float t[64][65];
  int z = blockIdx.z;
  const float* src = (z == 0 ? Wq : (z == 1 ? Wk : (z == 2 ? Wv : Wo)));
  u16* dst = (z == 0 ? WqT : (z == 1 ? WkT : (z == 2 ? WvT : WoT)));
  int tid = threadIdx.x;
  int bx = blockIdx.x, by = blockIdx.y;
  int c0 = by * 64;
  #pragma unroll
  for (int p = 0; p < 4; ++p){
    int rl = p * 16 + (tid >> 4);
    int srcRow = (z < 3) ? (bx * 64 + rl) : (rl * 16 + bx);
    float4 f = *(const float4*)(src + srcRow * 1024 + c0 + (tid & 15) * 4);
    t[rl][(tid & 15) * 4 + 0] = f.x;
    t[rl][(tid & 15) * 4 + 1] = f.y;
    t[rl][(tid & 15) * 4 + 2] = f.z;
    t[rl][(tid & 15) * 4 + 3] = f.w;
  }
  __syncthreads();
  int ro = tid >> 2;
  int kc = (tid & 3) * 16;
  int outBase = (c0 + ro) * 1024 + bx * 64;
  #pragma unroll
  for (int j = 0; j < 16; ++j)
    dst[outBase + kc + j] = f2bf(t[kc + j][ro]);
}

// ---------------- mask tile flags ----------------
__global__ void maskflag_kernel(const float* __restrict__ mask, u32* __restrict__ flags){
  int q0 = blockIdx.x * 128, k0 = blockIdx.y * 64;
  int tid = threadIdx.x;
  bool ok = true;
  #pragma unroll
  for (int p = 0; p < 8; ++p){
    int fi = p * 256 + tid;
    int r = fi >> 4, c = (fi & 15) * 4;
    float4 f = *(const float4*)(mask + (size_t)(q0 + r) * 1024 + k0 + c);
    ok = ok && (f.x == 1.0f) && (f.y == 1.0f) && (f.z == 1.0f) && (f.w == 1.0f);
  }
  __shared__ int s_ok[4];
  unsigned long long b = __ballot(ok);
  if ((tid & 63) == 0) s_ok[tid >> 6] = (b == ~0ull) ? 1 : 0;
  __syncthreads();
  if (tid == 0)
    flags[blockIdx.x * 16 + blockIdx.y] = (u32)(s_ok[0] & s_ok[1] & s_ok[2] & s_ok[3]);
}

// ---------------- QKV GEMM: 256x256 tile, 8 waves, phase-split schedule ----------------
struct QkvArgs {
  const u16* A[3]; const u16* BT[3]; const float* bias[3];
  u16* outQ; u16* outK; u16* outVT;
};

__global__ __launch_bounds__(512, 2)
void gemm_qkv_kernel(QkvArgs args){
  __shared__ __align__(16) u16 As[2][256 * 64];
  __shared__ __align__(16) u16 Bs[2][256 * 64];
  // XCD-chunked swizzle: 192 blocks, 192%8==0 -> bijective
  int wg = blockIdx.x;
  int l  = (wg & 7) * 24 + (wg >> 3);
  int z  = l >> 6;                       // 64 tiles per z
  int rem = l & 63;
  int m0 = (rem >> 2) * 256, n0 = (rem & 3) * 256;
  const u16* __restrict__ A  = args.A[z];
  const u16* __restrict__ BT = args.BT[z];
  const float* __restrict__ bias = args.bias[z];
  int tid = threadIdx.x, w = tid >> 6, lane = tid & 63, lr = lane & 15, lg = lane >> 4;
  int wm = w >> 2, wn = w & 3;           // wave grid 2 x 4; per-wave out 128 x 64

  auto stage = [&](int kt, int b){
    int k0 = kt * 64;
    #pragma unroll
    for (int r = 0; r < 4; ++r){
      int chunk = (r * 8 + w) * 1024;    // 32 wave-chunks of 1KB = 32KB per matrix
      int L = chunk + lane * 16;
      int row = L >> 7, inrow = L & 127;
      int srcB = inrow ^ ((row & 7) << 4);
      gload16(A + (m0 + row) * 1024 + k0 + (srcB >> 1), (char*)As[b] + chunk);
      gload16(BT + (n0 + row) * 1024 + k0 + (srcB >> 1), (char*)Bs[b] + chunk);
    }
  };
  stage(0, 0);

  f32x4 acc[8][4];
  #pragma unroll
  for (int i = 0; i < 8; ++i)
    #pragma unroll
    for (int j = 0; j < 4; ++j)
      acc[i][j] = f32x4{0.f, 0.f, 0.f, 0.f};

  for (int kt = 0; kt < 16; ++kt){
    int cur = kt & 1;
    // preamble: issue next tile's 8 loads, wait for current tile's 8 (counted)
    if (kt < 15){
      stage(kt + 1, cur ^ 1);
      asm volatile("s_waitcnt vmcnt(8)" ::: "memory");
    } else {
      asm volatile("s_waitcnt vmcnt(0)" ::: "memory");
    }

    short8 bf[4][2];
    #pragma unroll
    for (int p = 0; p < 4; ++p){
      asm volatile("" ::: "memory");
      __builtin_amdgcn_s_barrier();      // p==0: publishes buf[cur]; else phase align
      asm volatile("" ::: "memory");
      if (p == 0){
        #pragma unroll
        for (int j = 0; j < 4; ++j)
          #pragma unroll
          for (int kh = 0; kh < 2; ++kh){
            int rb = wn * 64 + j * 16 + lr;
            bf[j][kh] = *(const short8*)((const char*)Bs[cur] + rb * 128 +
                                         ((kh * 64 + lg * 16) ^ ((rb & 7) << 4)));
          }
      }
      short8 af[2][2];
      #pragma unroll
      for (int ii = 0; ii < 2; ++ii)
        #pragma unroll
        for (int kh = 0; kh < 2; ++kh){
          int ra = wm * 128 + (p * 2 + ii) * 16 + lr;
          af[ii][kh] = *(const short8*)((const char*)As[cur] + ra * 128 +
                                        ((kh * 64 + lg * 16) ^ ((ra & 7) << 4)));
        }
      __builtin_amdgcn_s_setprio(1);
      #pragma unroll
      for (int ii = 0; ii < 2; ++ii)
        #pragma unroll
        for (int j = 0; j < 4; ++j)
          #pragma unroll
          for (int kh = 0; kh < 2; ++kh)
            acc[p * 2 + ii][j] = __builtin_amdgcn_mfma_f32_16x16x32_bf16(
                af[ii][kh], bf[j][kh], acc[p * 2 + ii][j], 0, 0, 0);
      __builtin_amdgcn_s_setprio(0);
    }
    // end-of-tile barrier: all waves done reading buf[cur] before next preamble
    // overwrites buf[cur^1] (= buf read two tiles ago) and stages into it
    asm volatile("" ::: "memory");
    __builtin_amdgcn_s_barrier();
    asm volatile("" ::: "memory");
  }

  float bv[4];
  #pragma unroll
  for (int j = 0; j < 4; ++j) bv[j] = bias[n0 + wn * 64 + j * 16 + lr];
  float scale = (z == 0) ? 0.03125f : 1.0f;  // 1024^-0.5 for Q
  int bb = m0 >> 10;                          // tile never crosses batch boundary
  #pragma unroll
  for (int i = 0; i < 8; ++i){
    #pragma unroll
    for (int j = 0; j < 4; ++j){
      int gcol = n0 + wn * 64 + j * 16 + lr;
      int hh = gcol & 15, dd = gcol >> 4;
      #pragma unroll
      for (int rr = 0; rr < 4; ++rr){
        int grow = m0 + wm * 128 + i * 16 + lg * 4 + rr;
        int nn = grow & 1023;
        float vle = (acc[i][j][rr] + bv[j]) * scale;
        u16 ob = f2bf(vle);
        if (z == 2){
          args.outVT[((bb * 16 + hh) * 64 + dd) * 1024 + nn] = ob;   // V^T [b,h,d,n]
        } else {
          u16* o = (z == 0) ? args.outQ : args.outK;
          o[((bb * 16 + hh) * 1024 + nn) * 64 + dd] = ob;            // [b,h,n,d]
        }
      }
    }
  }
}

// ---------------- flash attention (swapped QK^T / swapped PV, dbuf K/V) ----------------
__global__ __launch_bounds__(256, 2)
void attn_kernel(const u16* __restrict__ Qh, const u16* __restrict__ Kh,
                 const u16* __restrict__ VT, const float* __restrict__ mask,
                 const u32* __restrict__ flags, u16* __restrict__ Oh){
  __shared__ __align__(16) u16 Qs[128 * 64];
  __shared__ __align__(16) u16 Ks[2][64 * 64];
  __shared__ __align__(16) u16 Vs[2][64 * 64];
  __shared__ __align__(16) u16 Ps[128 * 72];
  int tid = threadIdx.x, w = tid >> 6, lane = tid & 63, lr = lane & 15, lg = lane >> 4;
  int bh = blockIdx.y;
  int q0 = blockIdx.x * 128;
  const u16* Qb = Qh + (size_t)bh * 65536;
  const u16* Kb = Kh + (size_t)bh * 65536;
  const u16* Vb = VT + (size_t)bh * 65536;

  u32 fbits = 0;
  #pragma unroll
  for (int t = 0; t < 16; ++t) fbits |= (flags[blockIdx.x * 16 + t] & 1u) << t;

  #pragma unroll
  for (int r = 0; r < 4; ++r){
    int chunk = (r * 4 + w) * 1024;
    int L = chunk + lane * 16;
    int row = L >> 7, inrow = L & 127;
    int srcB = inrow ^ ((row & 7) << 4);
    gload16(Qb + (q0 + row) * 64 + (srcB >> 1), (char*)Qs + chunk);
  }

  auto stage_kv = [&](int t, int b){
    int kn = t * 64;
    #pragma unroll
    for (int r = 0; r < 2; ++r){
      int chunk = (r * 4 + w) * 1024;
      int L = chunk + lane * 16;
      int row = L >> 7, inrow = L & 127;
      int srcB = inrow ^ ((row & 7) << 4);
      gload16(Kb + (kn + row) * 64 + (srcB >> 1), (char*)Ks[b] + chunk);
      gload16(Vb + row * 1024 + kn + (srcB >> 1), (char*)Vs[b] + chunk);  // V^T rows = d
    }
  };
  stage_kv(0, 0);

  f32x4 o[2][4];
  float m_run[2], l_run[2];
  m_run[0] = m_run[1] = -3.0e38f;
  l_run[0] = l_run[1] = 0.f;
  #pragma unroll
  for (int i = 0; i < 2; ++i)
    #pragma unroll
    for (int j = 0; j < 4; ++j)
      o[i][j] = f32x4{0.f, 0.f, 0.f, 0.f};

  for (int kt = 0; kt < 16; ++kt){
    int cur = kt & 1;
    int kn0 = kt * 64;

    f32x4 s[2][4];
    if (fbits & (1u << kt)){
      #pragma unroll
      for (int i = 0; i < 2; ++i)
        #pragma unroll
        for (int j = 0; j < 4; ++j)
          s[i][j] = f32x4{0.f, 0.f, 0.f, 0.f};
    } else {
      #pragma unroll
      for (int i = 0; i < 2; ++i){
        int qg = q0 + w * 32 + i * 16 + lr;
        #pragma unroll
        for (int j = 0; j < 4; ++j){
          int kg = kn0 + j * 16 + lg * 4;
          float4 mm = *(const float4*)(mask + (size_t)qg * 1024 + kg);
          s[i][j][0] = fmaf(100000000.0f, mm.x, -100000000.0f);
          s[i][j][1] = fmaf(100000000.0f, mm.y, -100000000.0f);
          s[i][j][2] = fmaf(100000000.0f, mm.z, -100000000.0f);
          s[i][j][3] = fmaf(100000000.0f, mm.w, -100000000.0f);
        }
      }
    }

    if (kt < 15){
      stage_kv(kt + 1, cur ^ 1);
      asm volatile("s_waitcnt vmcnt(4)" ::: "memory");
    } else {
      asm volatile("s_waitcnt vmcnt(0)" ::: "memory");
    }
    __builtin_amdgcn_s_barrier();

    // QK^T swapped: s[i][j] = K_j^T x Q_i  -> C[k][q], col q = lr
    #pragma unroll
    for (int kh = 0; kh < 2; ++kh){
      short8 qf[2], kf[4];
      int cb = kh * 64 + lg * 16;
      #pragma unroll
      for (int i = 0; i < 2; ++i){
        int ra = w * 32 + i * 16 + lr;
        qf[i] = *(const short8*)((const char*)Qs + ra * 128 + (cb ^ ((ra & 7) << 4)));
      }
      #pragma unroll
      for (int j = 0; j < 4; ++j){
        int rb = j * 16 + lr;
        kf[j] = *(const short8*)((const char*)Ks[cur] + rb * 128 + (cb ^ ((rb & 7) << 4)));
      }
      #pragma unroll
      for (int i = 0; i < 2; ++i)
        #pragma unroll
        for (int j = 0; j < 4; ++j)
          s[i][j] = __builtin_amdgcn_mfma_f32_16x16x32_bf16(kf[j], qf[i], s[i][j], 0, 0, 0);
    }

    float alpha[2];
    #pragma unroll
    for (int i = 0; i < 2; ++i){
      float m0a = fmaxf(fmaxf(s[i][0][0], s[i][0][1]), fmaxf(s[i][0][2], s[i][0][3]));
      float m1a = fmaxf(fmaxf(s[i][1][0], s[i][1][1]), fmaxf(s[i][1][2], s[i][1][3]));
      float m2a = fmaxf(fmaxf(s[i][2][0], s[i][2][1]), fmaxf(s[i][2][2], s[i][2][3]));
      float m3a = fmaxf(fmaxf(s[i][3][0], s[i][3][1]), fmaxf(s[i][3][2], s[i][3][3]));
      float mx = fmaxf(fmaxf(m0a, m1a), fmaxf(m2a, m3a));
      mx = fmaxf(mx, __shfl_xor(mx, 16));
      mx = fmaxf(mx, __shfl_xor(mx, 32));
      float mnew = fmaxf(m_run[i], mx);
      alpha[i] = __expf(m_run[i] - mnew);
      m_run[i] = mnew;
      float rs = 0.f;
      #pragma unroll
      for (int j = 0; j < 4; ++j)
        #pragma unroll
        for (int rr = 0; rr < 4; ++rr){
          float p = __expf(s[i][j][rr] - mnew);
          s[i][j][rr] = p;
          rs += p;
        }
      rs += __shfl_xor(rs, 16);
      rs += __shfl_xor(rs, 32);
      l_run[i] = l_run[i] * alpha[i] + rs;
      int prow = w * 32 + i * 16 + lr;
      #pragma unroll
      for (int j = 0; j < 4; ++j){
        ushort4 pw;
        pw.x = f2bf(s[i][j][0]); pw.y = f2bf(s[i][j][1]);
        pw.z = f2bf(s[i][j][2]); pw.w = f2bf(s[i][j][3]);
        *(ushort4*)(Ps + prow * 72 + j * 16 + lg * 4) = pw;
      }
    }

    #pragma unroll
    for (int i = 0; i < 2; ++i)
      #pragma unroll
      for (int jd = 0; jd < 4; ++jd)
        #pragma unroll
        for (int rr = 0; rr < 4; ++rr)
          o[i][jd][rr] *= alpha[i];

    // PV swapped: o[i][jd] += V^T_jd x P_i  -> C[d][q], col q = lr
    #pragma unroll
    for (int kh = 0; kh < 2; ++kh){
      short8 pf[2], vf[4];
      int cb = kh * 64 + lg * 16;
      #pragma unroll
      for (int i = 0; i < 2; ++i){
        int ra = w * 32 + i * 16 + lr;
        pf[i] = *(const short8*)((const char*)Ps + ra * 144 + cb);
      }
      #pragma unroll
      for (int jd = 0; jd < 4; ++jd){
        int rb = jd * 16 + lr;
        vf[jd] = *(const short8*)((const char*)Vs[cur] + rb * 128 + (cb ^ ((rb & 7) << 4)));
      }
      #pragma unroll
      for (int i = 0; i < 2; ++i)
        #pragma unroll
        for (int jd = 0; jd < 4; ++jd)
          o[i][jd] = __builtin_amdgcn_mfma_f32_16x16x32_bf16(vf[jd], pf[i], o[i][jd], 0, 0, 0);
    }
    __builtin_amdgcn_s_barrier();
  }

  #pragma unroll
  for (int i = 0; i < 2; ++i){
    float inv = 1.0f / l_run[i];
    int qg = q0 + w * 32 + i * 16 + lr;
    #pragma unroll
    for (int jd = 0; jd < 4; ++jd){
      ushort4 ov;
      ov.x = f2bf(o[i][jd][0] * inv);
      ov.y = f2bf(o[i][jd][1] * inv);
      ov.z = f2bf(o[i][jd][2] * inv);
      ov.w = f2bf(o[i][jd][3] * inv);
      *(ushort4*)(Oh + ((size_t)bh * 1024 + qg) * 64 + jd * 16 + lg * 4) = ov;
    }
  }
}

// ---------------- output GEMM (dbuf + counted vmcnt + XCD swizzle) ----------------
__global__ __launch_bounds__(256, 2)
void gemm_out_kernel(const u16* __restrict__ Oh, const u16* __restrict__ WoT,
                     const float* __restrict__ bo, float* __restrict__ out){
  __shared__ __align__(16) u16 As[2][128 * 64];
  __shared__ __align__(16) u16 Bs[2][128 * 64];
  int wg = blockIdx.x;
  int l  = (wg & 7) * 32 + (wg >> 3);        // 256 blocks, bijective
  int m0 = (l >> 3) * 128, n0 = (l & 7) * 128;
  int tid = threadIdx.x, w = tid >> 6, lane = tid & 63, lr = lane & 15, lg = lane >> 4;
  int wr = w >> 1, wc = w & 1;
  f32x4 acc[4][4];
  #pragma unroll
  for (int i = 0; i < 4; ++i)
    #pragma unroll
    for (int j = 0; j < 4; ++j)
      acc[i][j] = f32x4{0.f, 0.f, 0.f, 0.f};

  auto stage = [&](int kt, int b){
    int k0 = kt * 64;
    #pragma unroll
    for (int r = 0; r < 4; ++r){
      int chunk = (r * 4 + w) * 1024;
      int L = chunk + lane * 16;
      int row = L >> 7, inrow = L & 127;
      int srcB = inrow ^ ((row & 7) << 4);
      int m = m0 + row;
      int bb = m >> 10, nn = m & 1023;
      gload16(Oh + ((size_t)(bb * 16 + kt) * 1024 + nn) * 64 + (srcB >> 1), (char*)As[b] + chunk);
      gload16(WoT + (n0 + row) * 1024 + k0 + (srcB >> 1), (char*)Bs[b] + chunk);
    }
  };
  stage(0, 0);

  for (int kt = 0; kt < 16; ++kt){   // kt == head index
    int cur = kt & 1;
    if (kt < 15){
      stage(kt + 1, cur ^ 1);
      asm volatile("s_waitcnt vmcnt(8)" ::: "memory");
    } else {
      asm volatile("s_waitcnt vmcnt(0)" ::: "memory");
    }
    __builtin_amdgcn_s_barrier();
    #pragma unroll
    for (int kh = 0; kh < 2; ++kh){
      short8 af[4], bfr[4];
      int cb = kh * 64 + lg * 16;
      #pragma unroll
      for (int i = 0; i < 4; ++i){
        int ra = wr * 64 + i * 16 + lr;
        af[i] = *(const short8*)((const char*)As[cur] + ra * 128 + (cb ^ ((ra & 7) << 4)));
        int rb = wc * 64 + i * 16 + lr;
        bfr[i] = *(const short8*)((const char*)Bs[cur] + rb * 128 + (cb ^ ((rb & 7) << 4)));
      }
      #pragma unroll
      for (int i = 0; i < 4; ++i)
        #pragma unroll
        for (int j = 0; j < 4; ++j)
          acc[i][j] = __builtin_amdgcn_mfma_f32_16x16x32_bf16(af[i], bfr[j], acc[i][j], 0, 0, 0);
    }
    __builtin_amdgcn_s_barrier();
  }

  float bv[4];
  #pragma unroll
  for (int j = 0; j < 4; ++j) bv[j] = bo[n0 + wc * 64 + j * 16 + lr];
  #pragma unroll
  for (int i = 0; i < 4; ++i)
    #pragma unroll
    for (int j = 0; j < 4; ++j){
      int gcol = n0 + wc * 64 + j * 16 + lr;
      #pragma unroll
      for (int rr = 0; rr < 4; ++rr){
        int grow = m0 + wr * 64 + i * 16 + lg * 4 + rr;
        out[(size_t)grow * 1024 + gcol] = acc[i][j][rr] + bv[j];
      }
    }
}

extern "C" void kernel_launch(void* const* d_in, const int* in_sizes, int n_in,
                              void* d_out, int out_size, void* d_ws, size_t ws_size,
                              hipStream_t stream){
  const float* q    = (const float*)d_in[0];
  const float* k    = (const float*)d_in[1];
  const float* v    = (const float*)d_in[2];
  const float* mask = (const float*)d_in[3];
  const float* Wq   = (const float*)d_in[4];
  const float* bq   = (const float*)d_in[5];
  const float* Wk   = (const float*)d_in[6];
  const float* bk   = (const float*)d_in[7];
  const float* Wv   = (const float*)d_in[8];
  const float* bv   = (const float*)d_in[9];
  const float* Wo   = (const float*)d_in[10];
  const float* bo   = (const float*)d_in[11];

  char* ws = (char*)d_ws;
  u16* Qh  = (u16*)(ws + (size_t)0);
  u16* Kh  = (u16*)(ws + ((size_t)8  << 20));
  u16* VT  = (u16*)(ws + ((size_t)16 << 20));
  u16* Oh  = (u16*)(ws + ((size_t)24 << 20));
  u16* Xq  = (u16*)(ws + ((size_t)32 << 20));
  u16* Xk  = (u16*)(ws + ((size_t)40 << 20));
  u16* Xv  = (u16*)(ws + ((size_t)48 << 20));
  u16* WqT = (u16*)(ws + ((size_t)56 << 20));
  u16* WkT = (u16*)(ws + ((size_t)58 << 20));
  u16* WvT = (u16*)(ws + ((size_t)60 << 20));
  u16* WoT = (u16*)(ws + ((size_t)62 << 20));
  u32* Flags = (u32*)(ws + ((size_t)32 << 20));  // reuses dead Xq region (after gemm_qkv)

  cast3_kernel<<<dim3(2048), dim3(256), 0, stream>>>(q, k, v, Xq, Xk, Xv);
  transw_kernel<<<dim3(16, 16, 4), dim3(256), 0, stream>>>(Wq, Wk, Wv, Wo, WqT, WkT, WvT, WoT);

  QkvArgs a;
  a.A[0] = Xq;  a.A[1] = Xk;  a.A[2] = Xv;
  a.BT[0] = WqT; a.BT[1] = WkT; a.BT[2] = WvT;
  a.bias[0] = bq; a.bias[1] = bk; a.bias[2] = bv;
  a.outQ = Qh; a.outK = Kh; a.outVT = VT;
  gemm_qkv_kernel<<<dim3(192), dim3(512), 0, stream>>>(a);

  maskflag_kernel<<<dim3(8, 16), dim3(256), 0, stream>>>(mask, Flags);
  attn_kernel<<<dim3(8, 64), dim3(256), 0, stream>>>(Qh, Kh, VT, mask, Flags, Oh);
  gemm_out_kernel<<<dim3(256), dim3(256), 0, stream>>>(Oh, WoT, bo, (float*)d_out);
}

// Round 7
// 164.634 us; speedup vs baseline: 1.0966x; 1.0966x over previous
//
#include <hip/hip_runtime.h>
#include <stdint.h>

typedef __attribute__((ext_vector_type(8))) short short8;
typedef __attribute__((ext_vector_type(8))) unsigned short ushort8;
typedef __attribute__((ext_vector_type(4))) float f32x4;
typedef unsigned short u16;
typedef unsigned int u32;

// RNE f32 -> bf16 bits
__device__ __forceinline__ u16 f2bf(float f){
  u32 u = __builtin_bit_cast(u32, f);
  u32 r = (u + 0x7fffu + ((u >> 16) & 1u)) >> 16;
  return (u16)r;
}

__device__ __forceinline__ void gload16(const void* g, void* l){
  __builtin_amdgcn_global_load_lds((const __attribute__((address_space(1))) void*)g,
                                   (__attribute__((address_space(3))) void*)l, 16, 0, 0);
}

// ---------------- cast q,k,v -> bf16 (16B stores) ----------------
__global__ void cast3_kernel(const float* __restrict__ q, const float* __restrict__ k,
                             const float* __restrict__ v, u16* __restrict__ xq,
                             u16* __restrict__ xk, u16* __restrict__ xv){
  const int NV8 = 4194304 / 8;
  int stride = gridDim.x * blockDim.x;
  for (int i = blockIdx.x * blockDim.x + threadIdx.x; i < 3 * NV8; i += stride){
    int t = i / NV8, r = i - t * NV8;
    const float4* src = (const float4*)(t == 0 ? q : (t == 1 ? k : v));
    u16* dst = (t == 0 ? xq : (t == 1 ? xk : xv));
    float4 f0 = src[r * 2], f1 = src[r * 2 + 1];
    ushort8 o;
    o[0] = f2bf(f0.x); o[1] = f2bf(f0.y); o[2] = f2bf(f0.z); o[3] = f2bf(f0.w);
    o[4] = f2bf(f1.x); o[5] = f2bf(f1.y); o[6] = f2bf(f1.z); o[7] = f2bf(f1.w);
    *(ushort8*)(dst + r * 8) = o;
  }
}

// ---------------- transpose + cast weights ----------------
__global__ void transw_kernel(const float* __restrict__ Wq, const float* __restrict__ Wk,
                              const float* __restrict__ Wv, const float* __restrict__ Wo,
                              u16* __restrict__ WqT, u16* __restrict__ WkT,
                              u16* __restrict__ WvT, u16* __restrict__ WoT){
  __shared__ float t[64][65];
  int z = blockIdx.z;
  const float* src = (z == 0 ? Wq : (z == 1 ? Wk : (z == 2 ? Wv : Wo)));
  u16* dst = (z == 0 ? WqT : (z == 1 ? WkT : (z == 2 ? WvT : WoT)));
  int tid = threadIdx.x;
  int bx = blockIdx.x, by = blockIdx.y;
  int c0 = by * 64;
  #pragma unroll
  for (int p = 0; p < 4; ++p){
    int rl = p * 16 + (tid >> 4);
    int srcRow = (z < 3) ? (bx * 64 + rl) : (rl * 16 + bx);
    float4 f = *(const float4*)(src + srcRow * 1024 + c0 + (tid & 15) * 4);
    t[rl][(tid & 15) * 4 + 0] = f.x;
    t[rl][(tid & 15) * 4 + 1] = f.y;
    t[rl][(tid & 15) * 4 + 2] = f.z;
    t[rl][(tid & 15) * 4 + 3] = f.w;
  }
  __syncthreads();
  int ro = tid >> 2;
  int kc = (tid & 3) * 16;
  int outBase = (c0 + ro) * 1024 + bx * 64;
  #pragma unroll
  for (int j = 0; j < 16; ++j)
    dst[outBase + kc + j] = f2bf(t[kc + j][ro]);
}

// ---------------- mask tile flags ----------------
__global__ void maskflag_kernel(const float* __restrict__ mask, u32* __restrict__ flags){
  int q0 = blockIdx.x * 128, k0 = blockIdx.y * 64;
  int tid = threadIdx.x;
  bool ok = true;
  #pragma unroll
  for (int p = 0; p < 8; ++p){
    int fi = p * 256 + tid;
    int r = fi >> 4, c = (fi & 15) * 4;
    float4 f = *(const float4*)(mask + (size_t)(q0 + r) * 1024 + k0 + c);
    ok = ok && (f.x == 1.0f) && (f.y == 1.0f) && (f.z == 1.0f) && (f.w == 1.0f);
  }
  __shared__ int s_ok[4];
  unsigned long long b = __ballot(ok);
  if ((tid & 63) == 0) s_ok[tid >> 6] = (b == ~0ull) ? 1 : 0;
  __syncthreads();
  if (tid == 0)
    flags[blockIdx.x * 16 + blockIdx.y] = (u32)(s_ok[0] & s_ok[1] & s_ok[2] & s_ok[3]);
}

// ---------------- QKV GEMM: r2 structure (single buf, syncthreads) + swizzle + lb(256,4) ----------------
struct QkvArgs {
  const u16* A[3]; const u16* BT[3]; const float* bias[3];
  u16* outQ; u16* outK; u16* outVT;
};

__global__ __launch_bounds__(256, 4)
void gemm_qkv_kernel(QkvArgs args){
  __shared__ __align__(16) u16 As[128 * 64];
  __shared__ __align__(16) u16 Bs[128 * 64];
  // XCD-chunked swizzle: 768 blocks, hw xcd = wg%8, contiguous chunk per XCD
  int wg = blockIdx.x;
  int l  = (wg & 7) * 96 + (wg >> 3);
  int z  = l >> 8;
  int rem = l & 255;
  int m0 = (rem >> 3) * 128, n0 = (rem & 7) * 128;
  const u16* __restrict__ A  = args.A[z];
  const u16* __restrict__ BT = args.BT[z];
  const float* __restrict__ bias = args.bias[z];
  int tid = threadIdx.x, w = tid >> 6, lane = tid & 63, lr = lane & 15, lg = lane >> 4;
  int wr = w >> 1, wc = w & 1;
  f32x4 acc[4][4];
  #pragma unroll
  for (int i = 0; i < 4; ++i)
    #pragma unroll
    for (int j = 0; j < 4; ++j)
      acc[i][j] = f32x4{0.f, 0.f, 0.f, 0.f};

  for (int kt = 0; kt < 16; ++kt){
    int k0 = kt * 64;
    #pragma unroll
    for (int r = 0; r < 4; ++r){
      int chunk = (r * 4 + w) * 1024;
      int L = chunk + lane * 16;
      int row = L >> 7, inrow = L & 127;
      int srcB = inrow ^ ((row & 7) << 4);
      gload16(A + (m0 + row) * 1024 + k0 + (srcB >> 1), (char*)As + chunk);
      gload16(BT + (n0 + row) * 1024 + k0 + (srcB >> 1), (char*)Bs + chunk);
    }
    __syncthreads();
    #pragma unroll
    for (int kh = 0; kh < 2; ++kh){
      short8 af[4], bfr[4];
      int cb = kh * 64 + lg * 16;
      #pragma unroll
      for (int i = 0; i < 4; ++i){
        int ra = wr * 64 + i * 16 + lr;
        af[i] = *(const short8*)((const char*)As + ra * 128 + (cb ^ ((ra & 7) << 4)));
        int rb = wc * 64 + i * 16 + lr;
        bfr[i] = *(const short8*)((const char*)Bs + rb * 128 + (cb ^ ((rb & 7) << 4)));
      }
      #pragma unroll
      for (int i = 0; i < 4; ++i)
        #pragma unroll
        for (int j = 0; j < 4; ++j)
          acc[i][j] = __builtin_amdgcn_mfma_f32_16x16x32_bf16(af[i], bfr[j], acc[i][j], 0, 0, 0);
    }
    __syncthreads();
  }

  float bv[4];
  #pragma unroll
  for (int j = 0; j < 4; ++j) bv[j] = bias[n0 + wc * 64 + j * 16 + lr];
  float scale = (z == 0) ? 0.03125f : 1.0f;  // 1024^-0.5 for Q
  #pragma unroll
  for (int i = 0; i < 4; ++i){
    #pragma unroll
    for (int j = 0; j < 4; ++j){
      int gcol = n0 + wc * 64 + j * 16 + lr;
      int hh = gcol & 15, dd = gcol >> 4;
      #pragma unroll
      for (int rr = 0; rr < 4; ++rr){
        int grow = m0 + wr * 64 + i * 16 + lg * 4 + rr;
        int bb = grow >> 10, nn = grow & 1023;
        float vle = (acc[i][j][rr] + bv[j]) * scale;
        u16 ob = f2bf(vle);
        if (z == 2){
          args.outVT[((bb * 16 + hh) * 64 + dd) * 1024 + nn] = ob;   // V^T [b,h,d,n]
        } else {
          u16* o = (z == 0) ? args.outQ : args.outK;
          o[((bb * 16 + hh) * 1024 + nn) * 64 + dd] = ob;            // [b,h,n,d]
        }
      }
    }
  }
}

// ---------------- flash attention (swapped QK^T / swapped PV, dbuf K/V) ----------------
__global__ __launch_bounds__(256, 2)
void attn_kernel(const u16* __restrict__ Qh, const u16* __restrict__ Kh,
                 const u16* __restrict__ VT, const float* __restrict__ mask,
                 const u32* __restrict__ flags, u16* __restrict__ Oh){
  __shared__ __align__(16) u16 Qs[128 * 64];
  __shared__ __align__(16) u16 Ks[2][64 * 64];
  __shared__ __align__(16) u16 Vs[2][64 * 64];
  __shared__ __align__(16) u16 Ps[128 * 72];
  int tid = threadIdx.x, w = tid >> 6, lane = tid & 63, lr = lane & 15, lg = lane >> 4;
  int bh = blockIdx.y;
  int q0 = blockIdx.x * 128;
  const u16* Qb = Qh + (size_t)bh * 65536;
  const u16* Kb = Kh + (size_t)bh * 65536;
  const u16* Vb = VT + (size_t)bh * 65536;

  u32 fbits = 0;
  #pragma unroll
  for (int t = 0; t < 16; ++t) fbits |= (flags[blockIdx.x * 16 + t] & 1u) << t;

  #pragma unroll
  for (int r = 0; r < 4; ++r){
    int chunk = (r * 4 + w) * 1024;
    int L = chunk + lane * 16;
    int row = L >> 7, inrow = L & 127;
    int srcB = inrow ^ ((row & 7) << 4);
    gload16(Qb + (q0 + row) * 64 + (srcB >> 1), (char*)Qs + chunk);
  }

  auto stage_kv = [&](int t, int b){
    int kn = t * 64;
    #pragma unroll
    for (int r = 0; r < 2; ++r){
      int chunk = (r * 4 + w) * 1024;
      int L = chunk + lane * 16;
      int row = L >> 7, inrow = L & 127;
      int srcB = inrow ^ ((row & 7) << 4);
      gload16(Kb + (kn + row) * 64 + (srcB >> 1), (char*)Ks[b] + chunk);
      gload16(Vb + row * 1024 + kn + (srcB >> 1), (char*)Vs[b] + chunk);  // V^T rows = d
    }
  };
  stage_kv(0, 0);

  f32x4 o[2][4];
  float m_run[2], l_run[2];
  m_run[0] = m_run[1] = -3.0e38f;
  l_run[0] = l_run[1] = 0.f;
  #pragma unroll
  for (int i = 0; i < 2; ++i)
    #pragma unroll
    for (int j = 0; j < 4; ++j)
      o[i][j] = f32x4{0.f, 0.f, 0.f, 0.f};

  for (int kt = 0; kt < 16; ++kt){
    int cur = kt & 1;
    int kn0 = kt * 64;

    f32x4 s[2][4];
    if (fbits & (1u << kt)){
      #pragma unroll
      for (int i = 0; i < 2; ++i)
        #pragma unroll
        for (int j = 0; j < 4; ++j)
          s[i][j] = f32x4{0.f, 0.f, 0.f, 0.f};
    } else {
      #pragma unroll
      for (int i = 0; i < 2; ++i){
        int qg = q0 + w * 32 + i * 16 + lr;
        #pragma unroll
        for (int j = 0; j < 4; ++j){
          int kg = kn0 + j * 16 + lg * 4;
          float4 mm = *(const float4*)(mask + (size_t)qg * 1024 + kg);
          s[i][j][0] = fmaf(100000000.0f, mm.x, -100000000.0f);
          s[i][j][1] = fmaf(100000000.0f, mm.y, -100000000.0f);
          s[i][j][2] = fmaf(100000000.0f, mm.z, -100000000.0f);
          s[i][j][3] = fmaf(100000000.0f, mm.w, -100000000.0f);
        }
      }
    }

    if (kt < 15){
      stage_kv(kt + 1, cur ^ 1);
      asm volatile("s_waitcnt vmcnt(4)" ::: "memory");
    } else {
      asm volatile("s_waitcnt vmcnt(0)" ::: "memory");
    }
    __builtin_amdgcn_s_barrier();

    // QK^T swapped: s[i][j] = K_j^T x Q_i  -> C[k][q], col q = lr
    #pragma unroll
    for (int kh = 0; kh < 2; ++kh){
      short8 qf[2], kf[4];
      int cb = kh * 64 + lg * 16;
      #pragma unroll
      for (int i = 0; i < 2; ++i){
        int ra = w * 32 + i * 16 + lr;
        qf[i] = *(const short8*)((const char*)Qs + ra * 128 + (cb ^ ((ra & 7) << 4)));
      }
      #pragma unroll
      for (int j = 0; j < 4; ++j){
        int rb = j * 16 + lr;
        kf[j] = *(const short8*)((const char*)Ks[cur] + rb * 128 + (cb ^ ((rb & 7) << 4)));
      }
      #pragma unroll
      for (int i = 0; i < 2; ++i)
        #pragma unroll
        for (int j = 0; j < 4; ++j)
          s[i][j] = __builtin_amdgcn_mfma_f32_16x16x32_bf16(kf[j], qf[i], s[i][j], 0, 0, 0);
    }

    float alpha[2];
    #pragma unroll
    for (int i = 0; i < 2; ++i){
      float m0a = fmaxf(fmaxf(s[i][0][0], s[i][0][1]), fmaxf(s[i][0][2], s[i][0][3]));
      float m1a = fmaxf(fmaxf(s[i][1][0], s[i][1][1]), fmaxf(s[i][1][2], s[i][1][3]));
      float m2a = fmaxf(fmaxf(s[i][2][0], s[i][2][1]), fmaxf(s[i][2][2], s[i][2][3]));
      float m3a = fmaxf(fmaxf(s[i][3][0], s[i][3][1]), fmaxf(s[i][3][2], s[i][3][3]));
      float mx = fmaxf(fmaxf(m0a, m1a), fmaxf(m2a, m3a));
      mx = fmaxf(mx, __shfl_xor(mx, 16));
      mx = fmaxf(mx, __shfl_xor(mx, 32));
      float mnew = fmaxf(m_run[i], mx);
      alpha[i] = __expf(m_run[i] - mnew);
      m_run[i] = mnew;
      float rs = 0.f;
      #pragma unroll
      for (int j = 0; j < 4; ++j)
        #pragma unroll
        for (int rr = 0; rr < 4; ++rr){
          float p = __expf(s[i][j][rr] - mnew);
          s[i][j][rr] = p;
          rs += p;
        }
      rs += __shfl_xor(rs, 16);
      rs += __shfl_xor(rs, 32);
      l_run[i] = l_run[i] * alpha[i] + rs;
      int prow = w * 32 + i * 16 + lr;
      #pragma unroll
      for (int j = 0; j < 4; ++j){
        ushort4 pw;
        pw.x = f2bf(s[i][j][0]); pw.y = f2bf(s[i][j][1]);
        pw.z = f2bf(s[i][j][2]); pw.w = f2bf(s[i][j][3]);
        *(ushort4*)(Ps + prow * 72 + j * 16 + lg * 4) = pw;
      }
    }

    #pragma unroll
    for (int i = 0; i < 2; ++i)
      #pragma unroll
      for (int jd = 0; jd < 4; ++jd)
        #pragma unroll
        for (int rr = 0; rr < 4; ++rr)
          o[i][jd][rr] *= alpha[i];

    // PV swapped: o[i][jd] += V^T_jd x P_i  -> C[d][q], col q = lr
    #pragma unroll
    for (int kh = 0; kh < 2; ++kh){
      short8 pf[2], vf[4];
      int cb = kh * 64 + lg * 16;
      #pragma unroll
      for (int i = 0; i < 2; ++i){
        int ra = w * 32 + i * 16 + lr;
        pf[i] = *(const short8*)((const char*)Ps + ra * 144 + cb);
      }
      #pragma unroll
      for (int jd = 0; jd < 4; ++jd){
        int rb = jd * 16 + lr;
        vf[jd] = *(const short8*)((const char*)Vs[cur] + rb * 128 + (cb ^ ((rb & 7) << 4)));
      }
      #pragma unroll
      for (int i = 0; i < 2; ++i)
        #pragma unroll
        for (int jd = 0; jd < 4; ++jd)
          o[i][jd] = __builtin_amdgcn_mfma_f32_16x16x32_bf16(vf[jd], pf[i], o[i][jd], 0, 0, 0);
    }
    __builtin_amdgcn_s_barrier();
  }

  #pragma unroll
  for (int i = 0; i < 2; ++i){
    float inv = 1.0f / l_run[i];
    int qg = q0 + w * 32 + i * 16 + lr;
    #pragma unroll
    for (int jd = 0; jd < 4; ++jd){
      ushort4 ov;
      ov.x = f2bf(o[i][jd][0] * inv);
      ov.y = f2bf(o[i][jd][1] * inv);
      ov.z = f2bf(o[i][jd][2] * inv);
      ov.w = f2bf(o[i][jd][3] * inv);
      *(ushort4*)(Oh + ((size_t)bh * 1024 + qg) * 64 + jd * 16 + lg * 4) = ov;
    }
  }
}

// ---------------- output GEMM: r2 structure + swizzle + lb(256,4) ----------------
__global__ __launch_bounds__(256, 4)
void gemm_out_kernel(const u16* __restrict__ Oh, const u16* __restrict__ WoT,
                     const float* __restrict__ bo, float* __restrict__ out){
  __shared__ __align__(16) u16 As[128 * 64];
  __shared__ __align__(16) u16 Bs[128 * 64];
  int wg = blockIdx.x;
  int l  = (wg & 7) * 32 + (wg >> 3);        // 256 blocks, bijective
  int m0 = (l >> 3) * 128, n0 = (l & 7) * 128;
  int tid = threadIdx.x, w = tid >> 6, lane = tid & 63, lr = lane & 15, lg = lane >> 4;
  int wr = w >> 1, wc = w & 1;
  f32x4 acc[4][4];
  #pragma unroll
  for (int i = 0; i < 4; ++i)
    #pragma unroll
    for (int j = 0; j < 4; ++j)
      acc[i][j] = f32x4{0.f, 0.f, 0.f, 0.f};

  for (int kt = 0; kt < 16; ++kt){   // kt == head index
    int k0 = kt * 64;
    #pragma unroll
    for (int r = 0; r < 4; ++r){
      int chunk = (r * 4 + w) * 1024;
      int L = chunk + lane * 16;
      int row = L >> 7, inrow = L & 127;
      int srcB = inrow ^ ((row & 7) << 4);
      int m = m0 + row;
      int bb = m >> 10, nn = m & 1023;
      gload16(Oh + ((size_t)(bb * 16 + kt) * 1024 + nn) * 64 + (srcB >> 1), (char*)As + chunk);
      gload16(WoT + (n0 + row) * 1024 + k0 + (srcB >> 1), (char*)Bs + chunk);
    }
    __syncthreads();
    #pragma unroll
    for (int kh = 0; kh < 2; ++kh){
      short8 af[4], bfr[4];
      int cb = kh * 64 + lg * 16;
      #pragma unroll
      for (int i = 0; i < 4; ++i){
        int ra = wr * 64 + i * 16 + lr;
        af[i] = *(const short8*)((const char*)As + ra * 128 + (cb ^ ((ra & 7) << 4)));
        int rb = wc * 64 + i * 16 + lr;
        bfr[i] = *(const short8*)((const char*)Bs + rb * 128 + (cb ^ ((rb & 7) << 4)));
      }
      #pragma unroll
      for (int i = 0; i < 4; ++i)
        #pragma unroll
        for (int j = 0; j < 4; ++j)
          acc[i][j] = __builtin_amdgcn_mfma_f32_16x16x32_bf16(af[i], bfr[j], acc[i][j], 0, 0, 0);
    }
    __syncthreads();
  }

  float bv[4];
  #pragma unroll
  for (int j = 0; j < 4; ++j) bv[j] = bo[n0 + wc * 64 + j * 16 + lr];
  #pragma unroll
  for (int i = 0; i < 4; ++i)
    #pragma unroll
    for (int j = 0; j < 4; ++j){
      int gcol = n0 + wc * 64 + j * 16 + lr;
      #pragma unroll
      for (int rr = 0; rr < 4; ++rr){
        int grow = m0 + wr * 64 + i * 16 + lg * 4 + rr;
        out[(size_t)grow * 1024 + gcol] = acc[i][j][rr] + bv[j];
      }
    }
}

extern "C" void kernel_launch(void* const* d_in, const int* in_sizes, int n_in,
                              void* d_out, int out_size, void* d_ws, size_t ws_size,
                              hipStream_t stream){
  const float* q    = (const float*)d_in[0];
  const float* k    = (const float*)d_in[1];
  const float* v    = (const float*)d_in[2];
  const float* mask = (const float*)d_in[3];
  const float* Wq   = (const float*)d_in[4];
  const float* bq   = (const float*)d_in[5];
  const float* Wk   = (const float*)d_in[6];
  const float* bk   = (const float*)d_in[7];
  const float* Wv   = (const float*)d_in[8];
  const float* bv   = (const float*)d_in[9];
  const float* Wo   = (const float*)d_in[10];
  const float* bo   = (const float*)d_in[11];

  char* ws = (char*)d_ws;
  u16* Qh  = (u16*)(ws + (size_t)0);
  u16* Kh  = (u16*)(ws + ((size_t)8  << 20));
  u16* VT  = (u16*)(ws + ((size_t)16 << 20));
  u16* Oh  = (u16*)(ws + ((size_t)24 << 20));
  u16* Xq  = (u16*)(ws + ((size_t)32 << 20));
  u16* Xk  = (u16*)(ws + ((size_t)40 << 20));
  u16* Xv  = (u16*)(ws + ((size_t)48 << 20));
  u16* WqT = (u16*)(ws + ((size_t)56 << 20));
  u16* WkT = (u16*)(ws + ((size_t)58 << 20));
  u16* WvT = (u16*)(ws + ((size_t)60 << 20));
  u16* WoT = (u16*)(ws + ((size_t)62 << 20));
  u32* Flags = (u32*)(ws + ((size_t)32 << 20));  // reuses dead Xq region (after gemm_qkv)

  cast3_kernel<<<dim3(2048), dim3(256), 0, stream>>>(q, k, v, Xq, Xk, Xv);
  transw_kernel<<<dim3(16, 16, 4), dim3(256), 0, stream>>>(Wq, Wk, Wv, Wo, WqT, WkT, WvT, WoT);

  QkvArgs a;
  a.A[0] = Xq;  a.A[1] = Xk;  a.A[2] = Xv;
  a.BT[0] = WqT; a.BT[1] = WkT; a.BT[2] = WvT;
  a.bias[0] = bq; a.bias[1] = bk; a.bias[2] = bv;
  a.outQ = Qh; a.outK = Kh; a.outVT = VT;
  gemm_qkv_kernel<<<dim3(768), dim3(256), 0, stream>>>(a);

  maskflag_kernel<<<dim3(8, 16), dim3(256), 0, stream>>>(mask, Flags);
  attn_kernel<<<dim3(8, 64), dim3(256), 0, stream>>>(Qh, Kh, VT, mask, Flags, Oh);
  gemm_out_kernel<<<dim3(256), dim3(256), 0, stream>>>(Oh, WoT, bo, (float*)d_out);
}

// Round 8
// 132.952 us; speedup vs baseline: 1.3579x; 1.2383x over previous
//
#include <hip/hip_runtime.h>
#include <stdint.h>

typedef __attribute__((ext_vector_type(8))) short short8;
typedef __attribute__((ext_vector_type(8))) unsigned short ushort8;
typedef __attribute__((ext_vector_type(4))) float f32x4;
typedef unsigned short u16;
typedef unsigned int u32;

// RNE f32 -> bf16 bits
__device__ __forceinline__ u16 f2bf(float f){
  u32 u = __builtin_bit_cast(u32, f);
  u32 r = (u + 0x7fffu + ((u >> 16) & 1u)) >> 16;
  return (u16)r;
}

__device__ __forceinline__ void gload16(const void* g, void* l){
  __builtin_amdgcn_global_load_lds((const __attribute__((address_space(1))) void*)g,
                                   (__attribute__((address_space(3))) void*)l, 16, 0, 0);
}

// ---------------- cast q,k,v -> bf16 (16B stores) ----------------
__global__ void cast3_kernel(const float* __restrict__ q, const float* __restrict__ k,
                             const float* __restrict__ v, u16* __restrict__ xq,
                             u16* __restrict__ xk, u16* __restrict__ xv){
  const int NV8 = 4194304 / 8;
  int stride = gridDim.x * blockDim.x;
  for (int i = blockIdx.x * blockDim.x + threadIdx.x; i < 3 * NV8; i += stride){
    int t = i / NV8, r = i - t * NV8;
    const float4* src = (const float4*)(t == 0 ? q : (t == 1 ? k : v));
    u16* dst = (t == 0 ? xq : (t == 1 ? xk : xv));
    float4 f0 = src[r * 2], f1 = src[r * 2 + 1];
    ushort8 o;
    o[0] = f2bf(f0.x); o[1] = f2bf(f0.y); o[2] = f2bf(f0.z); o[3] = f2bf(f0.w);
    o[4] = f2bf(f1.x); o[5] = f2bf(f1.y); o[6] = f2bf(f1.z); o[7] = f2bf(f1.w);
    *(ushort8*)(dst + r * 8) = o;
  }
}

// ---------------- transpose + cast weights ----------------
__global__ void transw_kernel(const float* __restrict__ Wq, const float* __restrict__ Wk,
                              const float* __restrict__ Wv, const float* __restrict__ Wo,
                              u16* __restrict__ WqT, u16* __restrict__ WkT,
                              u16* __restrict__ WvT, u16* __restrict__ WoT){
  __shared__ float t[64][65];
  int z = blockIdx.z;
  const float* src = (z == 0 ? Wq : (z == 1 ? Wk : (z == 2 ? Wv : Wo)));
  u16* dst = (z == 0 ? WqT : (z == 1 ? WkT : (z == 2 ? WvT : WoT)));
  int tid = threadIdx.x;
  int bx = blockIdx.x, by = blockIdx.y;
  int c0 = by * 64;
  #pragma unroll
  for (int p = 0; p < 4; ++p){
    int rl = p * 16 + (tid >> 4);
    int srcRow = (z < 3) ? (bx * 64 + rl) : (rl * 16 + bx);
    float4 f = *(const float4*)(src + srcRow * 1024 + c0 + (tid & 15) * 4);
    t[rl][(tid & 15) * 4 + 0] = f.x;
    t[rl][(tid & 15) * 4 + 1] = f.y;
    t[rl][(tid & 15) * 4 + 2] = f.z;
    t[rl][(tid & 15) * 4 + 3] = f.w;
  }
  __syncthreads();
  int ro = tid >> 2;
  int kc = (tid & 3) * 16;
  int outBase = (c0 + ro) * 1024 + bx * 64;
  #pragma unroll
  for (int j = 0; j < 16; ++j)
    dst[outBase + kc + j] = f2bf(t[kc + j][ro]);
}

// ---------------- mask tile flags ----------------
__global__ void maskflag_kernel(const float* __restrict__ mask, u32* __restrict__ flags){
  int q0 = blockIdx.x * 128, k0 = blockIdx.y * 64;
  int tid = threadIdx.x;
  bool ok = true;
  #pragma unroll
  for (int p = 0; p < 8; ++p){
    int fi = p * 256 + tid;
    int r = fi >> 4, c = (fi & 15) * 4;
    float4 f = *(const float4*)(mask + (size_t)(q0 + r) * 1024 + k0 + c);
    ok = ok && (f.x == 1.0f) && (f.y == 1.0f) && (f.z == 1.0f) && (f.w == 1.0f);
  }
  __shared__ int s_ok[4];
  unsigned long long b = __ballot(ok);
  if ((tid & 63) == 0) s_ok[tid >> 6] = (b == ~0ull) ? 1 : 0;
  __syncthreads();
  if (tid == 0)
    flags[blockIdx.x * 16 + blockIdx.y] = (u32)(s_ok[0] & s_ok[1] & s_ok[2] & s_ok[3]);
}

// ---------------- QKV GEMM: BK=32 dbuf (32KB LDS), counted vmcnt, XCD swizzle ----------------
struct QkvArgs {
  const u16* A[3]; const u16* BT[3]; const float* bias[3];
  u16* outQ; u16* outK; u16* outVT;
};

__global__ __launch_bounds__(256, 4)
void gemm_qkv_kernel(QkvArgs args){
  __shared__ __align__(16) u16 As[2][128 * 32];
  __shared__ __align__(16) u16 Bs[2][128 * 32];
  int wg = blockIdx.x;
  int l  = (wg & 7) * 96 + (wg >> 3);        // 768 blocks, bijective
  int z  = l >> 8;
  int rem = l & 255;
  int m0 = (rem >> 3) * 128, n0 = (rem & 7) * 128;
  const u16* __restrict__ A  = args.A[z];
  const u16* __restrict__ BT = args.BT[z];
  const float* __restrict__ bias = args.bias[z];
  int tid = threadIdx.x, w = tid >> 6, lane = tid & 63, lr = lane & 15, lg = lane >> 4;
  int wr = w >> 1, wc = w & 1;
  f32x4 acc[4][4];
  #pragma unroll
  for (int i = 0; i < 4; ++i)
    #pragma unroll
    for (int j = 0; j < 4; ++j)
      acc[i][j] = f32x4{0.f, 0.f, 0.f, 0.f};

  // stage one 128x32 tile of A and B into buffer b (2+2 gload16 per thread)
  auto stage = [&](int kt, int b){
    int k0 = kt * 32;
    #pragma unroll
    for (int p = 0; p < 2; ++p){
      int chunk = p * 4096 + w * 1024;            // wave-uniform LDS base
      int L = chunk + lane * 16;
      int row = L >> 6, inrow = L & 63;
      int srcB = inrow ^ ((row & 3) << 4);        // 64B-row swizzle
      gload16(A + (m0 + row) * 1024 + k0 + (srcB >> 1), (char*)As[b] + chunk);
      gload16(BT + (n0 + row) * 1024 + k0 + (srcB >> 1), (char*)Bs[b] + chunk);
    }
  };
  stage(0, 0);

  for (int kt = 0; kt < 32; ++kt){
    int cur = kt & 1;
    if (kt < 31){
      stage(kt + 1, cur ^ 1);
      asm volatile("s_waitcnt vmcnt(4)" ::: "memory");  // wait current tile only
    } else {
      asm volatile("s_waitcnt vmcnt(0)" ::: "memory");
    }
    __builtin_amdgcn_s_barrier();

    short8 af[4], bfr[4];
    int cb = lg * 16;
    #pragma unroll
    for (int i = 0; i < 4; ++i){
      int ra = wr * 64 + i * 16 + lr;
      af[i] = *(const short8*)((const char*)As[cur] + ra * 64 + (cb ^ ((ra & 3) << 4)));
      int rb = wc * 64 + i * 16 + lr;
      bfr[i] = *(const short8*)((const char*)Bs[cur] + rb * 64 + (cb ^ ((rb & 3) << 4)));
    }
    #pragma unroll
    for (int i = 0; i < 4; ++i)
      #pragma unroll
      for (int j = 0; j < 4; ++j)
        acc[i][j] = __builtin_amdgcn_mfma_f32_16x16x32_bf16(af[i], bfr[j], acc[i][j], 0, 0, 0);

    __builtin_amdgcn_s_barrier();   // all waves done reading cur before it is restaged
  }

  float bv[4];
  #pragma unroll
  for (int j = 0; j < 4; ++j) bv[j] = bias[n0 + wc * 64 + j * 16 + lr];
  float scale = (z == 0) ? 0.03125f : 1.0f;  // 1024^-0.5 for Q
  int bb = m0 >> 10;
  int dd0 = (n0 + wc * 64) >> 4;             // 4 consecutive dd via j, head hh = lr
  if (z == 2){
    // V^T [b,h,d,n]: rr gives 4 consecutive nn -> 8B stores
    #pragma unroll
    for (int i = 0; i < 4; ++i){
      int nn0 = (m0 + wr * 64 + i * 16 + lg * 4) & 1023;
      #pragma unroll
      for (int j = 0; j < 4; ++j){
        ushort4 pw;
        pw.x = f2bf((acc[i][j][0] + bv[j]) * scale);
        pw.y = f2bf((acc[i][j][1] + bv[j]) * scale);
        pw.z = f2bf((acc[i][j][2] + bv[j]) * scale);
        pw.w = f2bf((acc[i][j][3] + bv[j]) * scale);
        *(ushort4*)(args.outVT + ((size_t)(bb * 16 + lr) * 64 + dd0 + j) * 1024 + nn0) = pw;
      }
    }
  } else {
    // [b,h,n,d]: j gives 4 consecutive dd -> 8B stores
    u16* o = (z == 0) ? args.outQ : args.outK;
    #pragma unroll
    for (int i = 0; i < 4; ++i){
      #pragma unroll
      for (int rr = 0; rr < 4; ++rr){
        int nn = (m0 + wr * 64 + i * 16 + lg * 4 + rr) & 1023;
        ushort4 pw;
        pw.x = f2bf((acc[i][0][rr] + bv[0]) * scale);
        pw.y = f2bf((acc[i][1][rr] + bv[1]) * scale);
        pw.z = f2bf((acc[i][2][rr] + bv[2]) * scale);
        pw.w = f2bf((acc[i][3][rr] + bv[3]) * scale);
        *(ushort4*)(o + ((size_t)(bb * 16 + lr) * 1024 + nn) * 64 + dd0) = pw;
      }
    }
  }
}

// ---------------- flash attention (swapped QK^T / swapped PV, dbuf K/V) ----------------
__global__ __launch_bounds__(256, 2)
void attn_kernel(const u16* __restrict__ Qh, const u16* __restrict__ Kh,
                 const u16* __restrict__ VT, const float* __restrict__ mask,
                 const u32* __restrict__ flags, u16* __restrict__ Oh){
  __shared__ __align__(16) u16 Qs[128 * 64];
  __shared__ __align__(16) u16 Ks[2][64 * 64];
  __shared__ __align__(16) u16 Vs[2][64 * 64];
  __shared__ __align__(16) u16 Ps[128 * 72];
  int tid = threadIdx.x, w = tid >> 6, lane = tid & 63, lr = lane & 15, lg = lane >> 4;
  int bh = blockIdx.y;
  int q0 = blockIdx.x * 128;
  const u16* Qb = Qh + (size_t)bh * 65536;
  const u16* Kb = Kh + (size_t)bh * 65536;
  const u16* Vb = VT + (size_t)bh * 65536;

  u32 fbits = 0;
  #pragma unroll
  for (int t = 0; t < 16; ++t) fbits |= (flags[blockIdx.x * 16 + t] & 1u) << t;

  #pragma unroll
  for (int r = 0; r < 4; ++r){
    int chunk = (r * 4 + w) * 1024;
    int L = chunk + lane * 16;
    int row = L >> 7, inrow = L & 127;
    int srcB = inrow ^ ((row & 7) << 4);
    gload16(Qb + (q0 + row) * 64 + (srcB >> 1), (char*)Qs + chunk);
  }

  auto stage_kv = [&](int t, int b){
    int kn = t * 64;
    #pragma unroll
    for (int r = 0; r < 2; ++r){
      int chunk = (r * 4 + w) * 1024;
      int L = chunk + lane * 16;
      int row = L >> 7, inrow = L & 127;
      int srcB = inrow ^ ((row & 7) << 4);
      gload16(Kb + (kn + row) * 64 + (srcB >> 1), (char*)Ks[b] + chunk);
      gload16(Vb + row * 1024 + kn + (srcB >> 1), (char*)Vs[b] + chunk);  // V^T rows = d
    }
  };
  stage_kv(0, 0);

  f32x4 o[2][4];
  float m_run[2], l_run[2];
  m_run[0] = m_run[1] = -3.0e38f;
  l_run[0] = l_run[1] = 0.f;
  #pragma unroll
  for (int i = 0; i < 2; ++i)
    #pragma unroll
    for (int j = 0; j < 4; ++j)
      o[i][j] = f32x4{0.f, 0.f, 0.f, 0.f};

  for (int kt = 0; kt < 16; ++kt){
    int cur = kt & 1;
    int kn0 = kt * 64;

    f32x4 s[2][4];
    if (fbits & (1u << kt)){
      #pragma unroll
      for (int i = 0; i < 2; ++i)
        #pragma unroll
        for (int j = 0; j < 4; ++j)
          s[i][j] = f32x4{0.f, 0.f, 0.f, 0.f};
    } else {
      #pragma unroll
      for (int i = 0; i < 2; ++i){
        int qg = q0 + w * 32 + i * 16 + lr;
        #pragma unroll
        for (int j = 0; j < 4; ++j){
          int kg = kn0 + j * 16 + lg * 4;
          float4 mm = *(const float4*)(mask + (size_t)qg * 1024 + kg);
          s[i][j][0] = fmaf(100000000.0f, mm.x, -100000000.0f);
          s[i][j][1] = fmaf(100000000.0f, mm.y, -100000000.0f);
          s[i][j][2] = fmaf(100000000.0f, mm.z, -100000000.0f);
          s[i][j][3] = fmaf(100000000.0f, mm.w, -100000000.0f);
        }
      }
    }

    if (kt < 15){
      stage_kv(kt + 1, cur ^ 1);
      asm volatile("s_waitcnt vmcnt(4)" ::: "memory");
    } else {
      asm volatile("s_waitcnt vmcnt(0)" ::: "memory");
    }
    __builtin_amdgcn_s_barrier();

    // QK^T swapped: s[i][j] = K_j^T x Q_i  -> C[k][q], col q = lr
    #pragma unroll
    for (int kh = 0; kh < 2; ++kh){
      short8 qf[2], kf[4];
      int cb = kh * 64 + lg * 16;
      #pragma unroll
      for (int i = 0; i < 2; ++i){
        int ra = w * 32 + i * 16 + lr;
        qf[i] = *(const short8*)((const char*)Qs + ra * 128 + (cb ^ ((ra & 7) << 4)));
      }
      #pragma unroll
      for (int j = 0; j < 4; ++j){
        int rb = j * 16 + lr;
        kf[j] = *(const short8*)((const char*)Ks[cur] + rb * 128 + (cb ^ ((rb & 7) << 4)));
      }
      #pragma unroll
      for (int i = 0; i < 2; ++i)
        #pragma unroll
        for (int j = 0; j < 4; ++j)
          s[i][j] = __builtin_amdgcn_mfma_f32_16x16x32_bf16(kf[j], qf[i], s[i][j], 0, 0, 0);
    }

    float alpha[2];
    #pragma unroll
    for (int i = 0; i < 2; ++i){
      float m0a = fmaxf(fmaxf(s[i][0][0], s[i][0][1]), fmaxf(s[i][0][2], s[i][0][3]));
      float m1a = fmaxf(fmaxf(s[i][1][0], s[i][1][1]), fmaxf(s[i][1][2], s[i][1][3]));
      float m2a = fmaxf(fmaxf(s[i][2][0], s[i][2][1]), fmaxf(s[i][2][2], s[i][2][3]));
      float m3a = fmaxf(fmaxf(s[i][3][0], s[i][3][1]), fmaxf(s[i][3][2], s[i][3][3]));
      float mx = fmaxf(fmaxf(m0a, m1a), fmaxf(m2a, m3a));
      mx = fmaxf(mx, __shfl_xor(mx, 16));
      mx = fmaxf(mx, __shfl_xor(mx, 32));
      float mnew = fmaxf(m_run[i], mx);
      alpha[i] = __expf(m_run[i] - mnew);
      m_run[i] = mnew;
      float rs = 0.f;
      #pragma unroll
      for (int j = 0; j < 4; ++j)
        #pragma unroll
        for (int rr = 0; rr < 4; ++rr){
          float p = __expf(s[i][j][rr] - mnew);
          s[i][j][rr] = p;
          rs += p;
        }
      rs += __shfl_xor(rs, 16);
      rs += __shfl_xor(rs, 32);
      l_run[i] = l_run[i] * alpha[i] + rs;
      int prow = w * 32 + i * 16 + lr;
      #pragma unroll
      for (int j = 0; j < 4; ++j){
        ushort4 pw;
        pw.x = f2bf(s[i][j][0]); pw.y = f2bf(s[i][j][1]);
        pw.z = f2bf(s[i][j][2]); pw.w = f2bf(s[i][j][3]);
        *(ushort4*)(Ps + prow * 72 + j * 16 + lg * 4) = pw;
      }
    }

    #pragma unroll
    for (int i = 0; i < 2; ++i)
      #pragma unroll
      for (int jd = 0; jd < 4; ++jd)
        #pragma unroll
        for (int rr = 0; rr < 4; ++rr)
          o[i][jd][rr] *= alpha[i];

    // PV swapped: o[i][jd] += V^T_jd x P_i  -> C[d][q], col q = lr
    #pragma unroll
    for (int kh = 0; kh < 2; ++kh){
      short8 pf[2], vf[4];
      int cb = kh * 64 + lg * 16;
      #pragma unroll
      for (int i = 0; i < 2; ++i){
        int ra = w * 32 + i * 16 + lr;
        pf[i] = *(const short8*)((const char*)Ps + ra * 144 + cb);
      }
      #pragma unroll
      for (int jd = 0; jd < 4; ++jd){
        int rb = jd * 16 + lr;
        vf[jd] = *(const short8*)((const char*)Vs[cur] + rb * 128 + (cb ^ ((rb & 7) << 4)));
      }
      #pragma unroll
      for (int i = 0; i < 2; ++i)
        #pragma unroll
        for (int jd = 0; jd < 4; ++jd)
          o[i][jd] = __builtin_amdgcn_mfma_f32_16x16x32_bf16(vf[jd], pf[i], o[i][jd], 0, 0, 0);
    }
    __builtin_amdgcn_s_barrier();
  }

  #pragma unroll
  for (int i = 0; i < 2; ++i){
    float inv = 1.0f / l_run[i];
    int qg = q0 + w * 32 + i * 16 + lr;
    #pragma unroll
    for (int jd = 0; jd < 4; ++jd){
      ushort4 ov;
      ov.x = f2bf(o[i][jd][0] * inv);
      ov.y = f2bf(o[i][jd][1] * inv);
      ov.z = f2bf(o[i][jd][2] * inv);
      ov.w = f2bf(o[i][jd][3] * inv);
      *(ushort4*)(Oh + ((size_t)bh * 1024 + qg) * 64 + jd * 16 + lg * 4) = ov;
    }
  }
}

// ---------------- output GEMM: BK=32 dbuf (32KB LDS), counted vmcnt, XCD swizzle ----------------
__global__ __launch_bounds__(256, 4)
void gemm_out_kernel(const u16* __restrict__ Oh, const u16* __restrict__ WoT,
                     const float* __restrict__ bo, float* __restrict__ out){
  __shared__ __align__(16) u16 As[2][128 * 32];
  __shared__ __align__(16) u16 Bs[2][128 * 32];
  int wg = blockIdx.x;
  int l  = (wg & 7) * 32 + (wg >> 3);        // 256 blocks, bijective
  int m0 = (l >> 3) * 128, n0 = (l & 7) * 128;
  int tid = threadIdx.x, w = tid >> 6, lane = tid & 63, lr = lane & 15, lg = lane >> 4;
  int wr = w >> 1, wc = w & 1;
  f32x4 acc[4][4];
  #pragma unroll
  for (int i = 0; i < 4; ++i)
    #pragma unroll
    for (int j = 0; j < 4; ++j)
      acc[i][j] = f32x4{0.f, 0.f, 0.f, 0.f};

  auto stage = [&](int kt, int b){
    int hh = kt >> 1;                 // head index
    int dofs = (kt & 1) * 32;         // d-offset within head
    int k0 = kt * 32;
    #pragma unroll
    for (int p = 0; p < 2; ++p){
      int chunk = p * 4096 + w * 1024;
      int L = chunk + lane * 16;
      int row = L >> 6, inrow = L & 63;
      int srcB = inrow ^ ((row & 3) << 4);
      int m = m0 + row;
      int bb = m >> 10, nn = m & 1023;
      gload16(Oh + ((size_t)(bb * 16 + hh) * 1024 + nn) * 64 + dofs + (srcB >> 1),
              (char*)As[b] + chunk);
      gload16(WoT + (n0 + row) * 1024 + k0 + (srcB >> 1), (char*)Bs[b] + chunk);
    }
  };
  stage(0, 0);

  for (int kt = 0; kt < 32; ++kt){
    int cur = kt & 1;
    if (kt < 31){
      stage(kt + 1, cur ^ 1);
      asm volatile("s_waitcnt vmcnt(4)" ::: "memory");
    } else {
      asm volatile("s_waitcnt vmcnt(0)" ::: "memory");
    }
    __builtin_amdgcn_s_barrier();

    short8 af[4], bfr[4];
    int cb = lg * 16;
    #pragma unroll
    for (int i = 0; i < 4; ++i){
      int ra = wr * 64 + i * 16 + lr;
      af[i] = *(const short8*)((const char*)As[cur] + ra * 64 + (cb ^ ((ra & 3) << 4)));
      int rb = wc * 64 + i * 16 + lr;
      bfr[i] = *(const short8*)((const char*)Bs[cur] + rb * 64 + (cb ^ ((rb & 3) << 4)));
    }
    #pragma unroll
    for (int i = 0; i < 4; ++i)
      #pragma unroll
      for (int j = 0; j < 4; ++j)
        acc[i][j] = __builtin_amdgcn_mfma_f32_16x16x32_bf16(af[i], bfr[j], acc[i][j], 0, 0, 0);

    __builtin_amdgcn_s_barrier();
  }

  float bv[4];
  #pragma unroll
  for (int j = 0; j < 4; ++j) bv[j] = bo[n0 + wc * 64 + j * 16 + lr];
  #pragma unroll
  for (int i = 0; i < 4; ++i)
    #pragma unroll
    for (int j = 0; j < 4; ++j){
      int gcol = n0 + wc * 64 + j * 16 + lr;
      #pragma unroll
      for (int rr = 0; rr < 4; ++rr){
        int grow = m0 + wr * 64 + i * 16 + lg * 4 + rr;
        out[(size_t)grow * 1024 + gcol] = acc[i][j][rr] + bv[j];
      }
    }
}

extern "C" void kernel_launch(void* const* d_in, const int* in_sizes, int n_in,
                              void* d_out, int out_size, void* d_ws, size_t ws_size,
                              hipStream_t stream){
  const float* q    = (const float*)d_in[0];
  const float* k    = (const float*)d_in[1];
  const float* v    = (const float*)d_in[2];
  const float* mask = (const float*)d_in[3];
  const float* Wq   = (const float*)d_in[4];
  const float* bq   = (const float*)d_in[5];
  const float* Wk   = (const float*)d_in[6];
  const float* bk   = (const float*)d_in[7];
  const float* Wv   = (const float*)d_in[8];
  const float* bv   = (const float*)d_in[9];
  const float* Wo   = (const float*)d_in[10];
  const float* bo   = (const float*)d_in[11];

  char* ws = (char*)d_ws;
  u16* Qh  = (u16*)(ws + (size_t)0);
  u16* Kh  = (u16*)(ws + ((size_t)8  << 20));
  u16* VT  = (u16*)(ws + ((size_t)16 << 20));
  u16* Oh  = (u16*)(ws + ((size_t)24 << 20));
  u16* Xq  = (u16*)(ws + ((size_t)32 << 20));
  u16* Xk  = (u16*)(ws + ((size_t)40 << 20));
  u16* Xv  = (u16*)(ws + ((size_t)48 << 20));
  u16* WqT = (u16*)(ws + ((size_t)56 << 20));
  u16* WkT = (u16*)(ws + ((size_t)58 << 20));
  u16* WvT = (u16*)(ws + ((size_t)60 << 20));
  u16* WoT = (u16*)(ws + ((size_t)62 << 20));
  u32* Flags = (u32*)(ws + ((size_t)32 << 20));  // reuses dead Xq region (after gemm_qkv)

  cast3_kernel<<<dim3(2048), dim3(256), 0, stream>>>(q, k, v, Xq, Xk, Xv);
  transw_kernel<<<dim3(16, 16, 4), dim3(256), 0, stream>>>(Wq, Wk, Wv, Wo, WqT, WkT, WvT, WoT);

  QkvArgs a;
  a.A[0] = Xq;  a.A[1] = Xk;  a.A[2] = Xv;
  a.BT[0] = WqT; a.BT[1] = WkT; a.BT[2] = WvT;
  a.bias[0] = bq; a.bias[1] = bk; a.bias[2] = bv;
  a.outQ = Qh; a.outK = Kh; a.outVT = VT;
  gemm_qkv_kernel<<<dim3(768), dim3(256), 0, stream>>>(a);

  maskflag_kernel<<<dim3(8, 16), dim3(256), 0, stream>>>(mask, Flags);
  attn_kernel<<<dim3(8, 64), dim3(256), 0, stream>>>(Qh, Kh, VT, mask, Flags, Oh);
  gemm_out_kernel<<<dim3(256), dim3(256), 0, stream>>>(Oh, WoT, bo, (float*)d_out);
}

// Round 9
// 130.082 us; speedup vs baseline: 1.3879x; 1.0221x over previous
//
#include <hip/hip_runtime.h>
#include <stdint.h>

typedef __attribute__((ext_vector_type(8))) short short8;
typedef __attribute__((ext_vector_type(8))) unsigned short ushort8;
typedef __attribute__((ext_vector_type(4))) float f32x4;
typedef unsigned short u16;
typedef unsigned int u32;

// RNE f32 -> bf16 bits
__device__ __forceinline__ u16 f2bf(float f){
  u32 u = __builtin_bit_cast(u32, f);
  u32 r = (u + 0x7fffu + ((u >> 16) & 1u)) >> 16;
  return (u16)r;
}

__device__ __forceinline__ void gload16(const void* g, void* l){
  __builtin_amdgcn_global_load_lds((const __attribute__((address_space(1))) void*)g,
                                   (__attribute__((address_space(3))) void*)l, 16, 0, 0);
}

// ---------------- cast q,k,v -> bf16 (16B stores) ----------------
__global__ void cast3_kernel(const float* __restrict__ q, const float* __restrict__ k,
                             const float* __restrict__ v, u16* __restrict__ xq,
                             u16* __restrict__ xk, u16* __restrict__ xv){
  const int NV8 = 4194304 / 8;
  int stride = gridDim.x * blockDim.x;
  for (int i = blockIdx.x * blockDim.x + threadIdx.x; i < 3 * NV8; i += stride){
    int t = i / NV8, r = i - t * NV8;
    const float4* src = (const float4*)(t == 0 ? q : (t == 1 ? k : v));
    u16* dst = (t == 0 ? xq : (t == 1 ? xk : xv));
    float4 f0 = src[r * 2], f1 = src[r * 2 + 1];
    ushort8 o;
    o[0] = f2bf(f0.x); o[1] = f2bf(f0.y); o[2] = f2bf(f0.z); o[3] = f2bf(f0.w);
    o[4] = f2bf(f1.x); o[5] = f2bf(f1.y); o[6] = f2bf(f1.z); o[7] = f2bf(f1.w);
    *(ushort8*)(dst + r * 8) = o;
  }
}

// ---------------- transpose + cast weights ----------------
__global__ void transw_kernel(const float* __restrict__ Wq, const float* __restrict__ Wk,
                              const float* __restrict__ Wv, const float* __restrict__ Wo,
                              u16* __restrict__ WqT, u16* __restrict__ WkT,
                              u16* __restrict__ WvT, u16* __restrict__ WoT){
  __shared__ float t[64][65];
  int z = blockIdx.z;
  const float* src = (z == 0 ? Wq : (z == 1 ? Wk : (z == 2 ? Wv : Wo)));
  u16* dst = (z == 0 ? WqT : (z == 1 ? WkT : (z == 2 ? WvT : WoT)));
  int tid = threadIdx.x;
  int bx = blockIdx.x, by = blockIdx.y;
  int c0 = by * 64;
  #pragma unroll
  for (int p = 0; p < 4; ++p){
    int rl = p * 16 + (tid >> 4);
    int srcRow = (z < 3) ? (bx * 64 + rl) : (rl * 16 + bx);
    float4 f = *(const float4*)(src + srcRow * 1024 + c0 + (tid & 15) * 4);
    t[rl][(tid & 15) * 4 + 0] = f.x;
    t[rl][(tid & 15) * 4 + 1] = f.y;
    t[rl][(tid & 15) * 4 + 2] = f.z;
    t[rl][(tid & 15) * 4 + 3] = f.w;
  }
  __syncthreads();
  int ro = tid >> 2;
  int kc = (tid & 3) * 16;
  int outBase = (c0 + ro) * 1024 + bx * 64;
  #pragma unroll
  for (int j = 0; j < 16; ++j)
    dst[outBase + kc + j] = f2bf(t[kc + j][ro]);
}

// ---------------- mask tile flags ----------------
__global__ void maskflag_kernel(const float* __restrict__ mask, u32* __restrict__ flags){
  int q0 = blockIdx.x * 128, k0 = blockIdx.y * 64;
  int tid = threadIdx.x;
  bool ok = true;
  #pragma unroll
  for (int p = 0; p < 8; ++p){
    int fi = p * 256 + tid;
    int r = fi >> 4, c = (fi & 15) * 4;
    float4 f = *(const float4*)(mask + (size_t)(q0 + r) * 1024 + k0 + c);
    ok = ok && (f.x == 1.0f) && (f.y == 1.0f) && (f.z == 1.0f) && (f.w == 1.0f);
  }
  __shared__ int s_ok[4];
  unsigned long long b = __ballot(ok);
  if ((tid & 63) == 0) s_ok[tid >> 6] = (b == ~0ull) ? 1 : 0;
  __syncthreads();
  if (tid == 0)
    flags[blockIdx.x * 16 + blockIdx.y] = (u32)(s_ok[0] & s_ok[1] & s_ok[2] & s_ok[3]);
}

// ---------------- QKV GEMM: BK=32 dbuf, fixed swizzle (row bits 1-2), XCD swizzle ----------------
struct QkvArgs {
  const u16* A[3]; const u16* BT[3]; const float* bias[3];
  u16* outQ; u16* outK; u16* outVT;
};

__global__ __launch_bounds__(256, 4)
void gemm_qkv_kernel(QkvArgs args){
  __shared__ __align__(16) u16 As[2][128 * 32];
  __shared__ __align__(16) u16 Bs[2][128 * 32];
  int wg = blockIdx.x;
  int l  = (wg & 7) * 96 + (wg >> 3);        // 768 blocks, bijective
  int z  = l >> 8;
  int rem = l & 255;
  int m0 = (rem >> 3) * 128, n0 = (rem & 7) * 128;
  const u16* __restrict__ A  = args.A[z];
  const u16* __restrict__ BT = args.BT[z];
  const float* __restrict__ bias = args.bias[z];
  int tid = threadIdx.x, w = tid >> 6, lane = tid & 63, lr = lane & 15, lg = lane >> 4;
  int wr = w >> 1, wc = w & 1;
  f32x4 acc[4][4];
  #pragma unroll
  for (int i = 0; i < 4; ++i)
    #pragma unroll
    for (int j = 0; j < 4; ++j)
      acc[i][j] = f32x4{0.f, 0.f, 0.f, 0.f};

  // stage one 128x32 tile of A and B into buffer b (2+2 gload16 per thread)
  // swizzle uses row bits 1-2 (bit 0 is already the 16-bank row-parity offset)
  auto stage = [&](int kt, int b){
    int k0 = kt * 32;
    #pragma unroll
    for (int p = 0; p < 2; ++p){
      int chunk = p * 4096 + w * 1024;            // wave-uniform LDS base
      int L = chunk + lane * 16;
      int row = L >> 6, inrow = L & 63;
      int srcB = inrow ^ (((row >> 1) & 3) << 4);
      gload16(A + (m0 + row) * 1024 + k0 + (srcB >> 1), (char*)As[b] + chunk);
      gload16(BT + (n0 + row) * 1024 + k0 + (srcB >> 1), (char*)Bs[b] + chunk);
    }
  };
  stage(0, 0);

  for (int kt = 0; kt < 32; ++kt){
    int cur = kt & 1;
    if (kt < 31){
      stage(kt + 1, cur ^ 1);
      asm volatile("s_waitcnt vmcnt(4)" ::: "memory");  // wait current tile only
    } else {
      asm volatile("s_waitcnt vmcnt(0)" ::: "memory");
    }
    __builtin_amdgcn_s_barrier();

    short8 af[4], bfr[4];
    int cb = lg * 16;
    #pragma unroll
    for (int i = 0; i < 4; ++i){
      int ra = wr * 64 + i * 16 + lr;
      af[i] = *(const short8*)((const char*)As[cur] + ra * 64 + (cb ^ (((ra >> 1) & 3) << 4)));
      int rb = wc * 64 + i * 16 + lr;
      bfr[i] = *(const short8*)((const char*)Bs[cur] + rb * 64 + (cb ^ (((rb >> 1) & 3) << 4)));
    }
    #pragma unroll
    for (int i = 0; i < 4; ++i)
      #pragma unroll
      for (int j = 0; j < 4; ++j)
        acc[i][j] = __builtin_amdgcn_mfma_f32_16x16x32_bf16(af[i], bfr[j], acc[i][j], 0, 0, 0);

    __builtin_amdgcn_s_barrier();   // all waves done reading cur before it is restaged
  }

  float bv[4];
  #pragma unroll
  for (int j = 0; j < 4; ++j) bv[j] = bias[n0 + wc * 64 + j * 16 + lr];
  float scale = (z == 0) ? 0.03125f : 1.0f;  // 1024^-0.5 for Q
  int bb = m0 >> 10;
  int dd0 = (n0 + wc * 64) >> 4;             // 4 consecutive dd via j, head hh = lr
  if (z == 2){
    // V^T [b,h,d,n]: rr gives 4 consecutive nn -> 8B stores
    #pragma unroll
    for (int i = 0; i < 4; ++i){
      int nn0 = (m0 + wr * 64 + i * 16 + lg * 4) & 1023;
      #pragma unroll
      for (int j = 0; j < 4; ++j){
        ushort4 pw;
        pw.x = f2bf((acc[i][j][0] + bv[j]) * scale);
        pw.y = f2bf((acc[i][j][1] + bv[j]) * scale);
        pw.z = f2bf((acc[i][j][2] + bv[j]) * scale);
        pw.w = f2bf((acc[i][j][3] + bv[j]) * scale);
        *(ushort4*)(args.outVT + ((size_t)(bb * 16 + lr) * 64 + dd0 + j) * 1024 + nn0) = pw;
      }
    }
  } else {
    // [b,h,n,d]: j gives 4 consecutive dd -> 8B stores
    u16* o = (z == 0) ? args.outQ : args.outK;
    #pragma unroll
    for (int i = 0; i < 4; ++i){
      #pragma unroll
      for (int rr = 0; rr < 4; ++rr){
        int nn = (m0 + wr * 64 + i * 16 + lg * 4 + rr) & 1023;
        ushort4 pw;
        pw.x = f2bf((acc[i][0][rr] + bv[0]) * scale);
        pw.y = f2bf((acc[i][1][rr] + bv[1]) * scale);
        pw.z = f2bf((acc[i][2][rr] + bv[2]) * scale);
        pw.w = f2bf((acc[i][3][rr] + bv[3]) * scale);
        *(ushort4*)(o + ((size_t)(bb * 16 + lr) * 1024 + nn) * 64 + dd0) = pw;
      }
    }
  }
}

// ---------------- flash attention: XCD-swizzled grid (same-bh blocks share an XCD's L2) ----------------
__global__ __launch_bounds__(256, 2)
void attn_kernel(const u16* __restrict__ Qh, const u16* __restrict__ Kh,
                 const u16* __restrict__ VT, const float* __restrict__ mask,
                 const u32* __restrict__ flags, u16* __restrict__ Oh){
  __shared__ __align__(16) u16 Qs[128 * 64];
  __shared__ __align__(16) u16 Ks[2][64 * 64];
  __shared__ __align__(16) u16 Vs[2][64 * 64];
  __shared__ __align__(16) u16 Ps[128 * 72];
  int tid = threadIdx.x, w = tid >> 6, lane = tid & 63, lr = lane & 15, lg = lane >> 4;
  // 512 blocks, hw xcd = wg&7. Give each XCD 8 whole bh's (all 8 q-tiles each):
  int wg = blockIdx.x;
  int idx = wg >> 3;                       // 0..63 within XCD
  int bh = (wg & 7) * 8 + (idx >> 3);      // 8 bh per XCD
  int qt = idx & 7;                        // q-tile
  int q0 = qt * 128;
  const u16* Qb = Qh + (size_t)bh * 65536;
  const u16* Kb = Kh + (size_t)bh * 65536;
  const u16* Vb = VT + (size_t)bh * 65536;

  u32 fbits = 0;
  #pragma unroll
  for (int t = 0; t < 16; ++t) fbits |= (flags[qt * 16 + t] & 1u) << t;

  #pragma unroll
  for (int r = 0; r < 4; ++r){
    int chunk = (r * 4 + w) * 1024;
    int L = chunk + lane * 16;
    int row = L >> 7, inrow = L & 127;
    int srcB = inrow ^ ((row & 7) << 4);
    gload16(Qb + (q0 + row) * 64 + (srcB >> 1), (char*)Qs + chunk);
  }

  auto stage_kv = [&](int t, int b){
    int kn = t * 64;
    #pragma unroll
    for (int r = 0; r < 2; ++r){
      int chunk = (r * 4 + w) * 1024;
      int L = chunk + lane * 16;
      int row = L >> 7, inrow = L & 127;
      int srcB = inrow ^ ((row & 7) << 4);
      gload16(Kb + (kn + row) * 64 + (srcB >> 1), (char*)Ks[b] + chunk);
      gload16(Vb + row * 1024 + kn + (srcB >> 1), (char*)Vs[b] + chunk);  // V^T rows = d
    }
  };
  stage_kv(0, 0);

  f32x4 o[2][4];
  float m_run[2], l_run[2];
  m_run[0] = m_run[1] = -3.0e38f;
  l_run[0] = l_run[1] = 0.f;
  #pragma unroll
  for (int i = 0; i < 2; ++i)
    #pragma unroll
    for (int j = 0; j < 4; ++j)
      o[i][j] = f32x4{0.f, 0.f, 0.f, 0.f};

  for (int kt = 0; kt < 16; ++kt){
    int cur = kt & 1;
    int kn0 = kt * 64;

    f32x4 s[2][4];
    if (fbits & (1u << kt)){
      #pragma unroll
      for (int i = 0; i < 2; ++i)
        #pragma unroll
        for (int j = 0; j < 4; ++j)
          s[i][j] = f32x4{0.f, 0.f, 0.f, 0.f};
    } else {
      #pragma unroll
      for (int i = 0; i < 2; ++i){
        int qg = q0 + w * 32 + i * 16 + lr;
        #pragma unroll
        for (int j = 0; j < 4; ++j){
          int kg = kn0 + j * 16 + lg * 4;
          float4 mm = *(const float4*)(mask + (size_t)qg * 1024 + kg);
          s[i][j][0] = fmaf(100000000.0f, mm.x, -100000000.0f);
          s[i][j][1] = fmaf(100000000.0f, mm.y, -100000000.0f);
          s[i][j][2] = fmaf(100000000.0f, mm.z, -100000000.0f);
          s[i][j][3] = fmaf(100000000.0f, mm.w, -100000000.0f);
        }
      }
    }

    if (kt < 15){
      stage_kv(kt + 1, cur ^ 1);
      asm volatile("s_waitcnt vmcnt(4)" ::: "memory");
    } else {
      asm volatile("s_waitcnt vmcnt(0)" ::: "memory");
    }
    __builtin_amdgcn_s_barrier();

    // QK^T swapped: s[i][j] = K_j^T x Q_i  -> C[k][q], col q = lr
    #pragma unroll
    for (int kh = 0; kh < 2; ++kh){
      short8 qf[2], kf[4];
      int cb = kh * 64 + lg * 16;
      #pragma unroll
      for (int i = 0; i < 2; ++i){
        int ra = w * 32 + i * 16 + lr;
        qf[i] = *(const short8*)((const char*)Qs + ra * 128 + (cb ^ ((ra & 7) << 4)));
      }
      #pragma unroll
      for (int j = 0; j < 4; ++j){
        int rb = j * 16 + lr;
        kf[j] = *(const short8*)((const char*)Ks[cur] + rb * 128 + (cb ^ ((rb & 7) << 4)));
      }
      #pragma unroll
      for (int i = 0; i < 2; ++i)
        #pragma unroll
        for (int j = 0; j < 4; ++j)
          s[i][j] = __builtin_amdgcn_mfma_f32_16x16x32_bf16(kf[j], qf[i], s[i][j], 0, 0, 0);
    }

    float alpha[2];
    #pragma unroll
    for (int i = 0; i < 2; ++i){
      float m0a = fmaxf(fmaxf(s[i][0][0], s[i][0][1]), fmaxf(s[i][0][2], s[i][0][3]));
      float m1a = fmaxf(fmaxf(s[i][1][0], s[i][1][1]), fmaxf(s[i][1][2], s[i][1][3]));
      float m2a = fmaxf(fmaxf(s[i][2][0], s[i][2][1]), fmaxf(s[i][2][2], s[i][2][3]));
      float m3a = fmaxf(fmaxf(s[i][3][0], s[i][3][1]), fmaxf(s[i][3][2], s[i][3][3]));
      float mx = fmaxf(fmaxf(m0a, m1a), fmaxf(m2a, m3a));
      mx = fmaxf(mx, __shfl_xor(mx, 16));
      mx = fmaxf(mx, __shfl_xor(mx, 32));
      float mnew = fmaxf(m_run[i], mx);
      alpha[i] = __expf(m_run[i] - mnew);
      m_run[i] = mnew;
      float rs = 0.f;
      #pragma unroll
      for (int j = 0; j < 4; ++j)
        #pragma unroll
        for (int rr = 0; rr < 4; ++rr){
          float p = __expf(s[i][j][rr] - mnew);
          s[i][j][rr] = p;
          rs += p;
        }
      rs += __shfl_xor(rs, 16);
      rs += __shfl_xor(rs, 32);
      l_run[i] = l_run[i] * alpha[i] + rs;
      int prow = w * 32 + i * 16 + lr;
      #pragma unroll
      for (int j = 0; j < 4; ++j){
        ushort4 pw;
        pw.x = f2bf(s[i][j][0]); pw.y = f2bf(s[i][j][1]);
        pw.z = f2bf(s[i][j][2]); pw.w = f2bf(s[i][j][3]);
        *(ushort4*)(Ps + prow * 72 + j * 16 + lg * 4) = pw;
      }
    }

    #pragma unroll
    for (int i = 0; i < 2; ++i)
      #pragma unroll
      for (int jd = 0; jd < 4; ++jd)
        #pragma unroll
        for (int rr = 0; rr < 4; ++rr)
          o[i][jd][rr] *= alpha[i];

    // PV swapped: o[i][jd] += V^T_jd x P_i  -> C[d][q], col q = lr
    #pragma unroll
    for (int kh = 0; kh < 2; ++kh){
      short8 pf[2], vf[4];
      int cb = kh * 64 + lg * 16;
      #pragma unroll
      for (int i = 0; i < 2; ++i){
        int ra = w * 32 + i * 16 + lr;
        pf[i] = *(const short8*)((const char*)Ps + ra * 144 + cb);
      }
      #pragma unroll
      for (int jd = 0; jd < 4; ++jd){
        int rb = jd * 16 + lr;
        vf[jd] = *(const short8*)((const char*)Vs[cur] + rb * 128 + (cb ^ ((rb & 7) << 4)));
      }
      #pragma unroll
      for (int i = 0; i < 2; ++i)
        #pragma unroll
        for (int jd = 0; jd < 4; ++jd)
          o[i][jd] = __builtin_amdgcn_mfma_f32_16x16x32_bf16(vf[jd], pf[i], o[i][jd], 0, 0, 0);
    }
    __builtin_amdgcn_s_barrier();
  }

  #pragma unroll
  for (int i = 0; i < 2; ++i){
    float inv = 1.0f / l_run[i];
    int qg = q0 + w * 32 + i * 16 + lr;
    #pragma unroll
    for (int jd = 0; jd < 4; ++jd){
      ushort4 ov;
      ov.x = f2bf(o[i][jd][0] * inv);
      ov.y = f2bf(o[i][jd][1] * inv);
      ov.z = f2bf(o[i][jd][2] * inv);
      ov.w = f2bf(o[i][jd][3] * inv);
      *(ushort4*)(Oh + ((size_t)bh * 1024 + qg) * 64 + jd * 16 + lg * 4) = ov;
    }
  }
}

// ---------------- output GEMM: BK=32 dbuf, fixed swizzle, XCD swizzle ----------------
__global__ __launch_bounds__(256, 4)
void gemm_out_kernel(const u16* __restrict__ Oh, const u16* __restrict__ WoT,
                     const float* __restrict__ bo, float* __restrict__ out){
  __shared__ __align__(16) u16 As[2][128 * 32];
  __shared__ __align__(16) u16 Bs[2][128 * 32];
  int wg = blockIdx.x;
  int l  = (wg & 7) * 32 + (wg >> 3);        // 256 blocks, bijective
  int m0 = (l >> 3) * 128, n0 = (l & 7) * 128;
  int tid = threadIdx.x, w = tid >> 6, lane = tid & 63, lr = lane & 15, lg = lane >> 4;
  int wr = w >> 1, wc = w & 1;
  f32x4 acc[4][4];
  #pragma unroll
  for (int i = 0; i < 4; ++i)
    #pragma unroll
    for (int j = 0; j < 4; ++j)
      acc[i][j] = f32x4{0.f, 0.f, 0.f, 0.f};

  auto stage = [&](int kt, int b){
    int hh = kt >> 1;                 // head index
    int dofs = (kt & 1) * 32;         // d-offset within head
    int k0 = kt * 32;
    #pragma unroll
    for (int p = 0; p < 2; ++p){
      int chunk = p * 4096 + w * 1024;
      int L = chunk + lane * 16;
      int row = L >> 6, inrow = L & 63;
      int srcB = inrow ^ (((row >> 1) & 3) << 4);
      int m = m0 + row;
      int bb = m >> 10, nn = m & 1023;
      gload16(Oh + ((size_t)(bb * 16 + hh) * 1024 + nn) * 64 + dofs + (srcB >> 1),
              (char*)As[b] + chunk);
      gload16(WoT + (n0 + row) * 1024 + k0 + (srcB >> 1), (char*)Bs[b] + chunk);
    }
  };
  stage(0, 0);

  for (int kt = 0; kt < 32; ++kt){
    int cur = kt & 1;
    if (kt < 31){
      stage(kt + 1, cur ^ 1);
      asm volatile("s_waitcnt vmcnt(4)" ::: "memory");
    } else {
      asm volatile("s_waitcnt vmcnt(0)" ::: "memory");
    }
    __builtin_amdgcn_s_barrier();

    short8 af[4], bfr[4];
    int cb = lg * 16;
    #pragma unroll
    for (int i = 0; i < 4; ++i){
      int ra = wr * 64 + i * 16 + lr;
      af[i] = *(const short8*)((const char*)As[cur] + ra * 64 + (cb ^ (((ra >> 1) & 3) << 4)));
      int rb = wc * 64 + i * 16 + lr;
      bfr[i] = *(const short8*)((const char*)Bs[cur] + rb * 64 + (cb ^ (((rb >> 1) & 3) << 4)));
    }
    #pragma unroll
    for (int i = 0; i < 4; ++i)
      #pragma unroll
      for (int j = 0; j < 4; ++j)
        acc[i][j] = __builtin_amdgcn_mfma_f32_16x16x32_bf16(af[i], bfr[j], acc[i][j], 0, 0, 0);

    __builtin_amdgcn_s_barrier();
  }

  float bv[4];
  #pragma unroll
  for (int j = 0; j < 4; ++j) bv[j] = bo[n0 + wc * 64 + j * 16 + lr];
  #pragma unroll
  for (int i = 0; i < 4; ++i)
    #pragma unroll
    for (int j = 0; j < 4; ++j){
      int gcol = n0 + wc * 64 + j * 16 + lr;
      #pragma unroll
      for (int rr = 0; rr < 4; ++rr){
        int grow = m0 + wr * 64 + i * 16 + lg * 4 + rr;
        out[(size_t)grow * 1024 + gcol] = acc[i][j][rr] + bv[j];
      }
    }
}

extern "C" void kernel_launch(void* const* d_in, const int* in_sizes, int n_in,
                              void* d_out, int out_size, void* d_ws, size_t ws_size,
                              hipStream_t stream){
  const float* q    = (const float*)d_in[0];
  const float* k    = (const float*)d_in[1];
  const float* v    = (const float*)d_in[2];
  const float* mask = (const float*)d_in[3];
  const float* Wq   = (const float*)d_in[4];
  const float* bq   = (const float*)d_in[5];
  const float* Wk   = (const float*)d_in[6];
  const float* bk   = (const float*)d_in[7];
  const float* Wv   = (const float*)d_in[8];
  const float* bv   = (const float*)d_in[9];
  const float* Wo   = (const float*)d_in[10];
  const float* bo   = (const float*)d_in[11];

  char* ws = (char*)d_ws;
  u16* Qh  = (u16*)(ws + (size_t)0);
  u16* Kh  = (u16*)(ws + ((size_t)8  << 20));
  u16* VT  = (u16*)(ws + ((size_t)16 << 20));
  u16* Oh  = (u16*)(ws + ((size_t)24 << 20));
  u16* Xq  = (u16*)(ws + ((size_t)32 << 20));
  u16* Xk  = (u16*)(ws + ((size_t)40 << 20));
  u16* Xv  = (u16*)(ws + ((size_t)48 << 20));
  u16* WqT = (u16*)(ws + ((size_t)56 << 20));
  u16* WkT = (u16*)(ws + ((size_t)58 << 20));
  u16* WvT = (u16*)(ws + ((size_t)60 << 20));
  u16* WoT = (u16*)(ws + ((size_t)62 << 20));
  u32* Flags = (u32*)(ws + ((size_t)32 << 20));  // reuses dead Xq region (after gemm_qkv)

  cast3_kernel<<<dim3(2048), dim3(256), 0, stream>>>(q, k, v, Xq, Xk, Xv);
  transw_kernel<<<dim3(16, 16, 4), dim3(256), 0, stream>>>(Wq, Wk, Wv, Wo, WqT, WkT, WvT, WoT);

  QkvArgs a;
  a.A[0] = Xq;  a.A[1] = Xk;  a.A[2] = Xv;
  a.BT[0] = WqT; a.BT[1] = WkT; a.BT[2] = WvT;
  a.bias[0] = bq; a.bias[1] = bk; a.bias[2] = bv;
  a.outQ = Qh; a.outK = Kh; a.outVT = VT;
  gemm_qkv_kernel<<<dim3(768), dim3(256), 0, stream>>>(a);

  maskflag_kernel<<<dim3(8, 16), dim3(256), 0, stream>>>(mask, Flags);
  attn_kernel<<<dim3(512), dim3(256), 0, stream>>>(Qh, Kh, VT, mask, Flags, Oh);
  gemm_out_kernel<<<dim3(256), dim3(256), 0, stream>>>(Oh, WoT, bo, (float*)d_out);
}

// Round 10
// 125.436 us; speedup vs baseline: 1.4393x; 1.0370x over previous
//
#include <hip/hip_runtime.h>
#include <stdint.h>

typedef __attribute__((ext_vector_type(8))) short short8;
typedef __attribute__((ext_vector_type(8))) unsigned short ushort8;
typedef __attribute__((ext_vector_type(4))) float f32x4;
typedef unsigned short u16;
typedef unsigned int u32;

// RNE f32 -> bf16 bits
__device__ __forceinline__ u16 f2bf(float f){
  u32 u = __builtin_bit_cast(u32, f);
  u32 r = (u + 0x7fffu + ((u >> 16) & 1u)) >> 16;
  return (u16)r;
}

__device__ __forceinline__ void gload16(const void* g, void* l){
  __builtin_amdgcn_global_load_lds((const __attribute__((address_space(1))) void*)g,
                                   (__attribute__((address_space(3))) void*)l, 16, 0, 0);
}

// ---------------- fused prep: cast q,k,v -> bf16  +  transpose weights ----------------
__global__ void prep_kernel(const float* __restrict__ q, const float* __restrict__ k,
                            const float* __restrict__ v, u16* __restrict__ xq,
                            u16* __restrict__ xk, u16* __restrict__ xv,
                            const float* __restrict__ Wq, const float* __restrict__ Wk,
                            const float* __restrict__ Wv, const float* __restrict__ Wo,
                            u16* __restrict__ WqT, u16* __restrict__ WkT,
                            u16* __restrict__ WvT, u16* __restrict__ WoT){
  __shared__ float t[64][65];
  int bid = blockIdx.x;
  int tid = threadIdx.x;
  if (bid < 2048){
    // cast part: 3 * 524288 ushort8 items, grid-stride over 2048*256 threads
    const int NV8 = 4194304 / 8;
    for (int i = bid * 256 + tid; i < 3 * NV8; i += 2048 * 256){
      int tt = i / NV8, r = i - tt * NV8;
      const float4* src = (const float4*)(tt == 0 ? q : (tt == 1 ? k : v));
      u16* dst = (tt == 0 ? xq : (tt == 1 ? xk : xv));
      float4 f0 = src[r * 2], f1 = src[r * 2 + 1];
      ushort8 o;
      o[0] = f2bf(f0.x); o[1] = f2bf(f0.y); o[2] = f2bf(f0.z); o[3] = f2bf(f0.w);
      o[4] = f2bf(f1.x); o[5] = f2bf(f1.y); o[6] = f2bf(f1.z); o[7] = f2bf(f1.w);
      *(ushort8*)(dst + r * 8) = o;
    }
  } else {
    // transpose part: 1024 blocks -> (bx, by, z)
    int idx = bid - 2048;
    int bx = idx & 15, by = (idx >> 4) & 15, z = idx >> 8;
    const float* src = (z == 0 ? Wq : (z == 1 ? Wk : (z == 2 ? Wv : Wo)));
    u16* dst = (z == 0 ? WqT : (z == 1 ? WkT : (z == 2 ? WvT : WoT)));
    int c0 = by * 64;
    #pragma unroll
    for (int p = 0; p < 4; ++p){
      int rl = p * 16 + (tid >> 4);
      int srcRow = (z < 3) ? (bx * 64 + rl) : (rl * 16 + bx);
      float4 f = *(const float4*)(src + srcRow * 1024 + c0 + (tid & 15) * 4);
      t[rl][(tid & 15) * 4 + 0] = f.x;
      t[rl][(tid & 15) * 4 + 1] = f.y;
      t[rl][(tid & 15) * 4 + 2] = f.z;
      t[rl][(tid & 15) * 4 + 3] = f.w;
    }
    __syncthreads();
    int ro = tid >> 2;
    int kc = (tid & 3) * 16;
    int outBase = (c0 + ro) * 1024 + bx * 64;
    #pragma unroll
    for (int j = 0; j < 16; ++j)
      dst[outBase + kc + j] = f2bf(t[kc + j][ro]);
  }
}

// ---------------- mask tile flags ----------------
__global__ void maskflag_kernel(const float* __restrict__ mask, u32* __restrict__ flags){
  int q0 = blockIdx.x * 128, k0 = blockIdx.y * 64;
  int tid = threadIdx.x;
  bool ok = true;
  #pragma unroll
  for (int p = 0; p < 8; ++p){
    int fi = p * 256 + tid;
    int r = fi >> 4, c = (fi & 15) * 4;
    float4 f = *(const float4*)(mask + (size_t)(q0 + r) * 1024 + k0 + c);
    ok = ok && (f.x == 1.0f) && (f.y == 1.0f) && (f.z == 1.0f) && (f.w == 1.0f);
  }
  __shared__ int s_ok[4];
  unsigned long long b = __ballot(ok);
  if ((tid & 63) == 0) s_ok[tid >> 6] = (b == ~0ull) ? 1 : 0;
  __syncthreads();
  if (tid == 0)
    flags[blockIdx.x * 16 + blockIdx.y] = (u32)(s_ok[0] & s_ok[1] & s_ok[2] & s_ok[3]);
}

// ---------------- QKV GEMM: BK=32 TRIPLE buffer (prefetch dist 2), XCD swizzle ----------------
struct QkvArgs {
  const u16* A[3]; const u16* BT[3]; const float* bias[3];
  u16* outQ; u16* outK; u16* outVT;
};

__global__ __launch_bounds__(256, 3)
void gemm_qkv_kernel(QkvArgs args){
  __shared__ __align__(16) u16 As[3][128 * 32];
  __shared__ __align__(16) u16 Bs[3][128 * 32];
  int wg = blockIdx.x;
  int l  = (wg & 7) * 96 + (wg >> 3);        // 768 blocks, bijective
  int z  = l >> 8;
  int rem = l & 255;
  int m0 = (rem >> 3) * 128, n0 = (rem & 7) * 128;
  const u16* __restrict__ A  = args.A[z];
  const u16* __restrict__ BT = args.BT[z];
  const float* __restrict__ bias = args.bias[z];
  int tid = threadIdx.x, w = tid >> 6, lane = tid & 63, lr = lane & 15, lg = lane >> 4;
  int wr = w >> 1, wc = w & 1;
  f32x4 acc[4][4];
  #pragma unroll
  for (int i = 0; i < 4; ++i)
    #pragma unroll
    for (int j = 0; j < 4; ++j)
      acc[i][j] = f32x4{0.f, 0.f, 0.f, 0.f};

  auto stage = [&](int kt, int b){
    int k0 = kt * 32;
    #pragma unroll
    for (int p = 0; p < 2; ++p){
      int chunk = p * 4096 + w * 1024;            // wave-uniform LDS base
      int L = chunk + lane * 16;
      int row = L >> 6, inrow = L & 63;
      int srcB = inrow ^ (((row >> 1) & 3) << 4);
      gload16(A + (m0 + row) * 1024 + k0 + (srcB >> 1), (char*)As[b] + chunk);
      gload16(BT + (n0 + row) * 1024 + k0 + (srcB >> 1), (char*)Bs[b] + chunk);
    }
  };
  stage(0, 0);
  stage(1, 1);

  for (int kt = 0; kt < 32; ++kt){
    int cur = kt % 3;
    if (kt < 30){
      stage(kt + 2, (kt + 2) % 3);
      asm volatile("s_waitcnt vmcnt(8)" ::: "memory");  // tile kt's 4 loads done
    } else if (kt == 30){
      asm volatile("s_waitcnt vmcnt(4)" ::: "memory");
    } else {
      asm volatile("s_waitcnt vmcnt(0)" ::: "memory");
    }
    __builtin_amdgcn_s_barrier();

    short8 af[4], bfr[4];
    int cb = lg * 16;
    #pragma unroll
    for (int i = 0; i < 4; ++i){
      int ra = wr * 64 + i * 16 + lr;
      af[i] = *(const short8*)((const char*)As[cur] + ra * 64 + (cb ^ (((ra >> 1) & 3) << 4)));
      int rb = wc * 64 + i * 16 + lr;
      bfr[i] = *(const short8*)((const char*)Bs[cur] + rb * 64 + (cb ^ (((rb >> 1) & 3) << 4)));
    }
    #pragma unroll
    for (int i = 0; i < 4; ++i)
      #pragma unroll
      for (int j = 0; j < 4; ++j)
        acc[i][j] = __builtin_amdgcn_mfma_f32_16x16x32_bf16(af[i], bfr[j], acc[i][j], 0, 0, 0);

    __builtin_amdgcn_s_barrier();   // all waves done reading cur before it is restaged
  }

  float bv[4];
  #pragma unroll
  for (int j = 0; j < 4; ++j) bv[j] = bias[n0 + wc * 64 + j * 16 + lr];
  float scale = (z == 0) ? 0.03125f : 1.0f;  // 1024^-0.5 for Q
  int bb = m0 >> 10;
  int dd0 = (n0 + wc * 64) >> 4;             // 4 consecutive dd via j, head hh = lr
  if (z == 2){
    #pragma unroll
    for (int i = 0; i < 4; ++i){
      int nn0 = (m0 + wr * 64 + i * 16 + lg * 4) & 1023;
      #pragma unroll
      for (int j = 0; j < 4; ++j){
        ushort4 pw;
        pw.x = f2bf((acc[i][j][0] + bv[j]) * scale);
        pw.y = f2bf((acc[i][j][1] + bv[j]) * scale);
        pw.z = f2bf((acc[i][j][2] + bv[j]) * scale);
        pw.w = f2bf((acc[i][j][3] + bv[j]) * scale);
        *(ushort4*)(args.outVT + ((size_t)(bb * 16 + lr) * 64 + dd0 + j) * 1024 + nn0) = pw;
      }
    }
  } else {
    u16* o = (z == 0) ? args.outQ : args.outK;
    #pragma unroll
    for (int i = 0; i < 4; ++i){
      #pragma unroll
      for (int rr = 0; rr < 4; ++rr){
        int nn = (m0 + wr * 64 + i * 16 + lg * 4 + rr) & 1023;
        ushort4 pw;
        pw.x = f2bf((acc[i][0][rr] + bv[0]) * scale);
        pw.y = f2bf((acc[i][1][rr] + bv[1]) * scale);
        pw.z = f2bf((acc[i][2][rr] + bv[2]) * scale);
        pw.w = f2bf((acc[i][3][rr] + bv[3]) * scale);
        *(ushort4*)(o + ((size_t)(bb * 16 + lr) * 1024 + nn) * 64 + dd0) = pw;
      }
    }
  }
}

// ---------------- flash attention: XCD-swizzled grid (same-bh blocks share an XCD's L2) ----------------
__global__ __launch_bounds__(256, 2)
void attn_kernel(const u16* __restrict__ Qh, const u16* __restrict__ Kh,
                 const u16* __restrict__ VT, const float* __restrict__ mask,
                 const u32* __restrict__ flags, u16* __restrict__ Oh){
  __shared__ __align__(16) u16 Qs[128 * 64];
  __shared__ __align__(16) u16 Ks[2][64 * 64];
  __shared__ __align__(16) u16 Vs[2][64 * 64];
  __shared__ __align__(16) u16 Ps[128 * 72];
  int tid = threadIdx.x, w = tid >> 6, lane = tid & 63, lr = lane & 15, lg = lane >> 4;
  int wg = blockIdx.x;
  int idx = wg >> 3;
  int bh = (wg & 7) * 8 + (idx >> 3);
  int qt = idx & 7;
  int q0 = qt * 128;
  const u16* Qb = Qh + (size_t)bh * 65536;
  const u16* Kb = Kh + (size_t)bh * 65536;
  const u16* Vb = VT + (size_t)bh * 65536;

  u32 fbits = 0;
  #pragma unroll
  for (int t = 0; t < 16; ++t) fbits |= (flags[qt * 16 + t] & 1u) << t;

  #pragma unroll
  for (int r = 0; r < 4; ++r){
    int chunk = (r * 4 + w) * 1024;
    int L = chunk + lane * 16;
    int row = L >> 7, inrow = L & 127;
    int srcB = inrow ^ ((row & 7) << 4);
    gload16(Qb + (q0 + row) * 64 + (srcB >> 1), (char*)Qs + chunk);
  }

  auto stage_kv = [&](int t, int b){
    int kn = t * 64;
    #pragma unroll
    for (int r = 0; r < 2; ++r){
      int chunk = (r * 4 + w) * 1024;
      int L = chunk + lane * 16;
      int row = L >> 7, inrow = L & 127;
      int srcB = inrow ^ ((row & 7) << 4);
      gload16(Kb + (kn + row) * 64 + (srcB >> 1), (char*)Ks[b] + chunk);
      gload16(Vb + row * 1024 + kn + (srcB >> 1), (char*)Vs[b] + chunk);  // V^T rows = d
    }
  };
  stage_kv(0, 0);

  f32x4 o[2][4];
  float m_run[2], l_run[2];
  m_run[0] = m_run[1] = -3.0e38f;
  l_run[0] = l_run[1] = 0.f;
  #pragma unroll
  for (int i = 0; i < 2; ++i)
    #pragma unroll
    for (int j = 0; j < 4; ++j)
      o[i][j] = f32x4{0.f, 0.f, 0.f, 0.f};

  for (int kt = 0; kt < 16; ++kt){
    int cur = kt & 1;
    int kn0 = kt * 64;

    f32x4 s[2][4];
    if (fbits & (1u << kt)){
      #pragma unroll
      for (int i = 0; i < 2; ++i)
        #pragma unroll
        for (int j = 0; j < 4; ++j)
          s[i][j] = f32x4{0.f, 0.f, 0.f, 0.f};
    } else {
      #pragma unroll
      for (int i = 0; i < 2; ++i){
        int qg = q0 + w * 32 + i * 16 + lr;
        #pragma unroll
        for (int j = 0; j < 4; ++j){
          int kg = kn0 + j * 16 + lg * 4;
          float4 mm = *(const float4*)(mask + (size_t)qg * 1024 + kg);
          s[i][j][0] = fmaf(100000000.0f, mm.x, -100000000.0f);
          s[i][j][1] = fmaf(100000000.0f, mm.y, -100000000.0f);
          s[i][j][2] = fmaf(100000000.0f, mm.z, -100000000.0f);
          s[i][j][3] = fmaf(100000000.0f, mm.w, -100000000.0f);
        }
      }
    }

    if (kt < 15){
      stage_kv(kt + 1, cur ^ 1);
      asm volatile("s_waitcnt vmcnt(4)" ::: "memory");
    } else {
      asm volatile("s_waitcnt vmcnt(0)" ::: "memory");
    }
    __builtin_amdgcn_s_barrier();

    #pragma unroll
    for (int kh = 0; kh < 2; ++kh){
      short8 qf[2], kf[4];
      int cb = kh * 64 + lg * 16;
      #pragma unroll
      for (int i = 0; i < 2; ++i){
        int ra = w * 32 + i * 16 + lr;
        qf[i] = *(const short8*)((const char*)Qs + ra * 128 + (cb ^ ((ra & 7) << 4)));
      }
      #pragma unroll
      for (int j = 0; j < 4; ++j){
        int rb = j * 16 + lr;
        kf[j] = *(const short8*)((const char*)Ks[cur] + rb * 128 + (cb ^ ((rb & 7) << 4)));
      }
      #pragma unroll
      for (int i = 0; i < 2; ++i)
        #pragma unroll
        for (int j = 0; j < 4; ++j)
          s[i][j] = __builtin_amdgcn_mfma_f32_16x16x32_bf16(kf[j], qf[i], s[i][j], 0, 0, 0);
    }

    float alpha[2];
    #pragma unroll
    for (int i = 0; i < 2; ++i){
      float m0a = fmaxf(fmaxf(s[i][0][0], s[i][0][1]), fmaxf(s[i][0][2], s[i][0][3]));
      float m1a = fmaxf(fmaxf(s[i][1][0], s[i][1][1]), fmaxf(s[i][1][2], s[i][1][3]));
      float m2a = fmaxf(fmaxf(s[i][2][0], s[i][2][1]), fmaxf(s[i][2][2], s[i][2][3]));
      float m3a = fmaxf(fmaxf(s[i][3][0], s[i][3][1]), fmaxf(s[i][3][2], s[i][3][3]));
      float mx = fmaxf(fmaxf(m0a, m1a), fmaxf(m2a, m3a));
      mx = fmaxf(mx, __shfl_xor(mx, 16));
      mx = fmaxf(mx, __shfl_xor(mx, 32));
      float mnew = fmaxf(m_run[i], mx);
      alpha[i] = __expf(m_run[i] - mnew);
      m_run[i] = mnew;
      float rs = 0.f;
      #pragma unroll
      for (int j = 0; j < 4; ++j)
        #pragma unroll
        for (int rr = 0; rr < 4; ++rr){
          float p = __expf(s[i][j][rr] - mnew);
          s[i][j][rr] = p;
          rs += p;
        }
      rs += __shfl_xor(rs, 16);
      rs += __shfl_xor(rs, 32);
      l_run[i] = l_run[i] * alpha[i] + rs;
      int prow = w * 32 + i * 16 + lr;
      #pragma unroll
      for (int j = 0; j < 4; ++j){
        ushort4 pw;
        pw.x = f2bf(s[i][j][0]); pw.y = f2bf(s[i][j][1]);
        pw.z = f2bf(s[i][j][2]); pw.w = f2bf(s[i][j][3]);
        *(ushort4*)(Ps + prow * 72 + j * 16 + lg * 4) = pw;
      }
    }

    #pragma unroll
    for (int i = 0; i < 2; ++i)
      #pragma unroll
      for (int jd = 0; jd < 4; ++jd)
        #pragma unroll
        for (int rr = 0; rr < 4; ++rr)
          o[i][jd][rr] *= alpha[i];

    #pragma unroll
    for (int kh = 0; kh < 2; ++kh){
      short8 pf[2], vf[4];
      int cb = kh * 64 + lg * 16;
      #pragma unroll
      for (int i = 0; i < 2; ++i){
        int ra = w * 32 + i * 16 + lr;
        pf[i] = *(const short8*)((const char*)Ps + ra * 144 + cb);
      }
      #pragma unroll
      for (int jd = 0; jd < 4; ++jd){
        int rb = jd * 16 + lr;
        vf[jd] = *(const short8*)((const char*)Vs[cur] + rb * 128 + (cb ^ ((rb & 7) << 4)));
      }
      #pragma unroll
      for (int i = 0; i < 2; ++i)
        #pragma unroll
        for (int jd = 0; jd < 4; ++jd)
          o[i][jd] = __builtin_amdgcn_mfma_f32_16x16x32_bf16(vf[jd], pf[i], o[i][jd], 0, 0, 0);
    }
    __builtin_amdgcn_s_barrier();
  }

  #pragma unroll
  for (int i = 0; i < 2; ++i){
    float inv = 1.0f / l_run[i];
    int qg = q0 + w * 32 + i * 16 + lr;
    #pragma unroll
    for (int jd = 0; jd < 4; ++jd){
      ushort4 ov;
      ov.x = f2bf(o[i][jd][0] * inv);
      ov.y = f2bf(o[i][jd][1] * inv);
      ov.z = f2bf(o[i][jd][2] * inv);
      ov.w = f2bf(o[i][jd][3] * inv);
      *(ushort4*)(Oh + ((size_t)bh * 1024 + qg) * 64 + jd * 16 + lg * 4) = ov;
    }
  }
}

// ---------------- output GEMM: 128x64 tiles (512 blocks), BK=32 triple buffer ----------------
__global__ __launch_bounds__(256, 4)
void gemm_out_kernel(const u16* __restrict__ Oh, const u16* __restrict__ WoT,
                     const float* __restrict__ bo, float* __restrict__ out){
  __shared__ __align__(16) u16 As[3][128 * 32];
  __shared__ __align__(16) u16 Bs[3][64 * 32];
  int wg = blockIdx.x;
  int l  = (wg & 7) * 64 + (wg >> 3);        // 512 blocks, bijective
  int m0 = (l >> 4) * 128, n0 = (l & 15) * 64;
  int tid = threadIdx.x, w = tid >> 6, lane = tid & 63, lr = lane & 15, lg = lane >> 4;
  int wm = w >> 1, wn = w & 1;               // per-wave out 64(m) x 32(n)
  f32x4 acc[4][2];
  #pragma unroll
  for (int i = 0; i < 4; ++i)
    #pragma unroll
    for (int j = 0; j < 2; ++j)
      acc[i][j] = f32x4{0.f, 0.f, 0.f, 0.f};

  auto stage = [&](int kt, int b){
    int hh = kt >> 1;                 // head index
    int dofs = (kt & 1) * 32;         // d-offset within head
    int k0 = kt * 32;
    #pragma unroll
    for (int p = 0; p < 2; ++p){      // A: 8KB
      int chunk = p * 4096 + w * 1024;
      int L = chunk + lane * 16;
      int row = L >> 6, inrow = L & 63;
      int srcB = inrow ^ (((row >> 1) & 3) << 4);
      int m = m0 + row;
      int bb = m >> 10, nn = m & 1023;
      gload16(Oh + ((size_t)(bb * 16 + hh) * 1024 + nn) * 64 + dofs + (srcB >> 1),
              (char*)As[b] + chunk);
    }
    {                                  // B: 4KB (one gload16 per thread)
      int chunk = w * 1024;
      int L = chunk + lane * 16;
      int row = L >> 6, inrow = L & 63;
      int srcB = inrow ^ (((row >> 1) & 3) << 4);
      gload16(WoT + (n0 + row) * 1024 + k0 + (srcB >> 1), (char*)Bs[b] + chunk);
    }
  };
  stage(0, 0);
  stage(1, 1);

  for (int kt = 0; kt < 32; ++kt){
    int cur = kt % 3;
    if (kt < 30){
      stage(kt + 2, (kt + 2) % 3);
      asm volatile("s_waitcnt vmcnt(6)" ::: "memory");
    } else if (kt == 30){
      asm volatile("s_waitcnt vmcnt(3)" ::: "memory");
    } else {
      asm volatile("s_waitcnt vmcnt(0)" ::: "memory");
    }
    __builtin_amdgcn_s_barrier();

    short8 af[4], bfr[2];
    int cb = lg * 16;
    #pragma unroll
    for (int i = 0; i < 4; ++i){
      int ra = wm * 64 + i * 16 + lr;
      af[i] = *(const short8*)((const char*)As[cur] + ra * 64 + (cb ^ (((ra >> 1) & 3) << 4)));
    }
    #pragma unroll
    for (int j = 0; j < 2; ++j){
      int rb = wn * 32 + j * 16 + lr;
      bfr[j] = *(const short8*)((const char*)Bs[cur] + rb * 64 + (cb ^ (((rb >> 1) & 3) << 4)));
    }
    #pragma unroll
    for (int i = 0; i < 4; ++i)
      #pragma unroll
      for (int j = 0; j < 2; ++j)
        acc[i][j] = __builtin_amdgcn_mfma_f32_16x16x32_bf16(af[i], bfr[j], acc[i][j], 0, 0, 0);

    __builtin_amdgcn_s_barrier();
  }

  float bv[2];
  #pragma unroll
  for (int j = 0; j < 2; ++j) bv[j] = bo[n0 + wn * 32 + j * 16 + lr];
  #pragma unroll
  for (int i = 0; i < 4; ++i)
    #pragma unroll
    for (int j = 0; j < 2; ++j){
      int gcol = n0 + wn * 32 + j * 16 + lr;
      #pragma unroll
      for (int rr = 0; rr < 4; ++rr){
        int grow = m0 + wm * 64 + i * 16 + lg * 4 + rr;
        out[(size_t)grow * 1024 + gcol] = acc[i][j][rr] + bv[j];
      }
    }
}

extern "C" void kernel_launch(void* const* d_in, const int* in_sizes, int n_in,
                              void* d_out, int out_size, void* d_ws, size_t ws_size,
                              hipStream_t stream){
  const float* q    = (const float*)d_in[0];
  const float* k    = (const float*)d_in[1];
  const float* v    = (const float*)d_in[2];
  const float* mask = (const float*)d_in[3];
  const float* Wq   = (const float*)d_in[4];
  const float* bq   = (const float*)d_in[5];
  const float* Wk   = (const float*)d_in[6];
  const float* bk   = (const float*)d_in[7];
  const float* Wv   = (const float*)d_in[8];
  const float* bv   = (const float*)d_in[9];
  const float* Wo   = (const float*)d_in[10];
  const float* bo   = (const float*)d_in[11];

  char* ws = (char*)d_ws;
  u16* Qh  = (u16*)(ws + (size_t)0);
  u16* Kh  = (u16*)(ws + ((size_t)8  << 20));
  u16* VT  = (u16*)(ws + ((size_t)16 << 20));
  u16* Oh  = (u16*)(ws + ((size_t)24 << 20));
  u16* Xq  = (u16*)(ws + ((size_t)32 << 20));
  u16* Xk  = (u16*)(ws + ((size_t)40 << 20));
  u16* Xv  = (u16*)(ws + ((size_t)48 << 20));
  u16* WqT = (u16*)(ws + ((size_t)56 << 20));
  u16* WkT = (u16*)(ws + ((size_t)58 << 20));
  u16* WvT = (u16*)(ws + ((size_t)60 << 20));
  u16* WoT = (u16*)(ws + ((size_t)62 << 20));
  u32* Flags = (u32*)(ws + ((size_t)32 << 20));  // reuses dead Xq region (after gemm_qkv)

  prep_kernel<<<dim3(3072), dim3(256), 0, stream>>>(q, k, v, Xq, Xk, Xv,
                                                    Wq, Wk, Wv, Wo, WqT, WkT, WvT, WoT);

  QkvArgs a;
  a.A[0] = Xq;  a.A[1] = Xk;  a.A[2] = Xv;
  a.BT[0] = WqT; a.BT[1] = WkT; a.BT[2] = WvT;
  a.bias[0] = bq; a.bias[1] = bk; a.bias[2] = bv;
  a.outQ = Qh; a.outK = Kh; a.outVT = VT;
  gemm_qkv_kernel<<<dim3(768), dim3(256), 0, stream>>>(a);

  maskflag_kernel<<<dim3(8, 16), dim3(256), 0, stream>>>(mask, Flags);
  attn_kernel<<<dim3(512), dim3(256), 0, stream>>>(Qh, Kh, VT, mask, Flags, Oh);
  gemm_out_kernel<<<dim3(512), dim3(256), 0, stream>>>(Oh, WoT, bo, (float*)d_out);
}